// Round 13
// baseline (482.570 us; speedup 1.0000x reference)
//
#include <hip/hip_runtime.h>
#include <hip/hip_bf16.h>
#include <math.h>
#include <stdint.h>

typedef __hip_bfloat16 bf16;
typedef __attribute__((ext_vector_type(8))) short short8;
typedef __attribute__((ext_vector_type(4))) float f32x4;

#define B_SZ   16
#define HH     56
#define WW2    56
#define L_TOK  3136
#define C_DIM  192
#define NH_    6
#define DH     32
#define WS_    7
#define SS_    3
#define NW     49
#define NWIN   64
#define BWIN   (B_SZ*NWIN)  // 1024
#define TOK    (BWIN*NW)    // 50176
#define HID_   768

__device__ __forceinline__ float b2f(bf16 x){ return __bfloat162float(x); }
__device__ __forceinline__ bf16  f2b(float x){ return __float2bfloat16(x); }
__device__ __forceinline__ short f2bs(float x){ bf16 h = __float2bfloat16(x); return *reinterpret_cast<short*>(&h); }

// async global->LDS, 16B per lane; LDS dest = wave-uniform base + lane*16
__device__ __forceinline__ void gload16(const void* g, void* l) {
    __builtin_amdgcn_global_load_lds(
        (const __attribute__((address_space(1))) void*)(uintptr_t)g,
        (__attribute__((address_space(3))) void*)(uintptr_t)l, 16, 0, 0);
}

__device__ __forceinline__ float wave_sum64(float v){
    #pragma unroll
    for (int off = 32; off > 0; off >>= 1) v += __shfl_xor(v, off, 64);
    return v;
}

// ---------------------------------------------------------------------------
// LN1(se), LN1(de), copy(co) + cyclic shift + window partition.
// ---------------------------------------------------------------------------
__global__ void prep_kernel(const float* __restrict__ se, const float* __restrict__ de,
                            const float* __restrict__ co,
                            const float* __restrict__ g1s, const float* __restrict__ b1s,
                            const float* __restrict__ g1d, const float* __restrict__ b1d,
                            bf16* __restrict__ sw, bf16* __restrict__ dw, bf16* __restrict__ cw)
{
    int t   = blockIdx.x;
    int tid = threadIdx.x;
    int b_  = t / NW, n = t % NW;
    int b   = b_ / NWIN, w = b_ % NWIN;
    int wh  = w >> 3, wwi = w & 7;
    int i   = n / WS_, j = n % WS_;
    int hs  = wh*WS_ + i, ws = wwi*WS_ + j;
    int hsrc = hs + SS_; if (hsrc >= HH)  hsrc -= HH;
    int wsrc = ws + SS_; if (wsrc >= WW2) wsrc -= WW2;
    long src = ((long)(b*L_TOK + hsrc*WW2 + wsrc)) * C_DIM;
    long dst = (long)t * C_DIM;

    {
        float x0 = se[src+tid], x1 = se[src+tid+64], x2 = se[src+tid+128];
        float s  = wave_sum64(x0+x1+x2);
        float ss = wave_sum64(x0*x0 + x1*x1 + x2*x2);
        float mean = s * (1.0f/192.0f);
        float var  = ss * (1.0f/192.0f) - mean*mean;
        float rstd = rsqrtf(var + 1e-5f);
        sw[dst+tid]     = f2b((x0-mean)*rstd*g1s[tid]     + b1s[tid]);
        sw[dst+tid+64]  = f2b((x1-mean)*rstd*g1s[tid+64]  + b1s[tid+64]);
        sw[dst+tid+128] = f2b((x2-mean)*rstd*g1s[tid+128] + b1s[tid+128]);
    }
    {
        float x0 = de[src+tid], x1 = de[src+tid+64], x2 = de[src+tid+128];
        float s  = wave_sum64(x0+x1+x2);
        float ss = wave_sum64(x0*x0 + x1*x1 + x2*x2);
        float mean = s * (1.0f/192.0f);
        float var  = ss * (1.0f/192.0f) - mean*mean;
        float rstd = rsqrtf(var + 1e-5f);
        dw[dst+tid]     = f2b((x0-mean)*rstd*g1d[tid]     + b1d[tid]);
        dw[dst+tid+64]  = f2b((x1-mean)*rstd*g1d[tid+64]  + b1d[tid+64]);
        dw[dst+tid+128] = f2b((x2-mean)*rstd*g1d[tid+128] + b1d[tid+128]);
    }
    cw[dst+tid]     = f2b(co[src+tid]);
    cw[dst+tid+64]  = f2b(co[src+tid+64]);
    cw[dst+tid+128] = f2b(co[src+tid+128]);
}

// ---------------------------------------------------------------------------
// Weight pre-convert: fp32 [K][N] -> bf16 MFMA-B-fragment order.
// ---------------------------------------------------------------------------
__global__ __launch_bounds__(256)
void wconv(const float* w0,const float* w1,const float* w2,const float* w3,const float* w4,
           const float* w5,const float* w6,const float* w7,const float* w8, short* dst)
{
    const float* src; int K, N; long doff;
    switch (blockIdx.y) {
      case 0: src=w0; K=384; N=192; doff=0;      break;
      case 1: src=w1; K=384; N=192; doff=73728;  break;
      case 2: src=w2; K=192; N=384; doff=147456; break;
      case 3: src=w3; K=192; N=192; doff=221184; break;
      case 4: src=w4; K=192; N=192; doff=258048; break;
      case 5: src=w5; K=192; N=768; doff=294912; break;
      case 6: src=w6; K=768; N=192; doff=442368; break;
      case 7: src=w7; K=192; N=768; doff=589824; break;
      default:src=w8; K=768; N=192; doff=737280; break;
    }
    int nblk = (K>>5)*(N>>6);
    int bid = blockIdx.x;
    if (bid >= nblk) return;
    int kb = bid / (N>>6), nb = bid % (N>>6);
    __shared__ float tile[32][65];
    int tid = threadIdx.x;
    #pragma unroll
    for (int it = 0; it < 8; ++it) {
        int idx = tid + it*256;
        int r = idx >> 6, c = idx & 63;
        tile[r][c] = src[(long)(kb*32 + r)*N + nb*64 + c];
    }
    __syncthreads();
    int lane = tid & 63, nl = tid >> 6;
    short8 v;
    #pragma unroll
    for (int j = 0; j < 8; ++j)
        v[j] = f2bs(tile[(lane>>4)*8 + j][nl*16 + (lane&15)]);
    long nig = (long)nb*4 + nl;
    *(short8*)(dst + doff + (((long)kb*(N>>4) + nig)*64 + lane)*8) = v;
}

// ---------------------------------------------------------------------------
// fgemm2: C = A(bf16) @ Wfrag(bf16) + bias. MR16 16-row slices per tile.
// MODE 0 plain / 1 qk-scatter / 2 v-scatter
// ---------------------------------------------------------------------------
template<int MODE, bool DUAL, int MR16>
__global__ __launch_bounds__(384)
void fgemm2(const bf16* __restrict__ A1, const bf16* __restrict__ A2, int K1, int K,
            const short* __restrict__ wf, const float* __restrict__ bias, int Nn,
            bf16* __restrict__ out, bf16* __restrict__ out2,
            const bf16* __restrict__ A1b, const bf16* __restrict__ A2b,
            const short* __restrict__ wfB, const float* __restrict__ biasB,
            bf16* __restrict__ outB, int nxblk)
{
    __shared__ short AsF[2][MR16][64][8];
    const int MROWS = MR16 * 16;
    const int MPW   = MR16 / 2;
    int tid = threadIdx.x;
    int wid = tid >> 6, lane = tid & 63;
    int wr = (wid >= 3) ? 1 : 0, wc = wid - wr*3;
    int l15 = lane & 15, g = lane >> 4;

    int bx = blockIdx.x;
    const bf16 *A1p = A1, *A2p = A2; const short* wfp = wf;
    const float* biasp = bias; bf16* outp = out;
    if (DUAL && bx >= nxblk) {
        bx -= nxblk; A1p = A1b; A2p = A2b; wfp = wfB; biasp = biasB; outp = outB;
    }
    int row0 = bx * MROWS, col0 = blockIdx.y * 192;
    const int ntiles = Nn >> 4;

    f32x4 acc[MPW][4];
    #pragma unroll
    for (int m = 0; m < MPW; m++)
        #pragma unroll
        for (int n = 0; n < 4; n++)
            acc[m][n] = (f32x4){0.f,0.f,0.f,0.f};

    int nk = K >> 5;
    #define STAGE(buf_, k0_) {                                                   \
        int colk = (k0_) + (g << 3);                                             \
        const bf16* asrc = (colk < K1) ? A1p : A2p;                              \
        int kc = (colk < K1) ? colk : colk - K1;                                 \
        if (wid < MR16)                                                          \
            gload16(asrc + (long)(row0 + wid*16 + l15)*K1 + kc,                  \
                    &AsF[buf_][wid][0][0]);                                      \
        if (MR16 == 8 && wid < 2)                                                \
            gload16(asrc + (long)(row0 + (6+wid)*16 + l15)*K1 + kc,              \
                    &AsF[buf_][(MR16==8 ? 6+wid : 0)][0][0]);                    \
    }

    STAGE(0, 0);
    __syncthreads();
    for (int t = 0; t < nk; ++t) {
        int buf = t & 1;
        if (t + 1 < nk) STAGE(buf ^ 1, (t+1) << 5);
        short8 af[MPW], bf4[4];
        #pragma unroll
        for (int m = 0; m < MPW; m++) af[m] = *((short8*)&AsF[buf][wr*MPW + m][lane][0]);
        const short* wbase = wfp + (((long)t*ntiles + (col0>>4) + wc*4)*64 + lane)*8;
        #pragma unroll
        for (int n = 0; n < 4; n++) bf4[n] = *(const short8*)(wbase + n*512);
        #pragma unroll
        for (int m = 0; m < MPW; m++)
            #pragma unroll
            for (int n = 0; n < 4; n++)
                acc[m][n] = __builtin_amdgcn_mfma_f32_16x16x32_bf16(af[m], bf4[n], acc[m][n], 0, 0, 0);
        __syncthreads();
    }
    #undef STAGE

    #pragma unroll
    for (int m = 0; m < MPW; m++) {
        #pragma unroll
        for (int rr = 0; rr < 4; rr++) {
            int t = row0 + wr*(MROWS/2) + m*16 + g*4 + rr;
            #pragma unroll
            for (int n2 = 0; n2 < 4; n2++) {
                int oc = col0 + wc*64 + n2*16 + l15;
                float v = acc[m][n2][rr] + biasp[oc];
                if (MODE == 0) {
                    outp[(long)t*Nn + oc] = f2b(v);
                } else if (MODE == 1) {
                    int b_ = t / NW, n = t % NW;
                    if (oc < C_DIM) {
                        int head = oc >> 5, d = oc & 31;
                        outp[(((long)b_*NH_ + head)*NW + n)*DH + d] = f2b(v * 0.17677669529663687f);
                    } else {
                        int och = oc - C_DIM;
                        int head = och >> 5, d = och & 31;
                        out2[(((long)b_*NH_ + head)*NW + n)*DH + d] = f2b(v);
                    }
                } else { // MODE 2
                    int b_ = t / NW, n = t % NW;
                    int head = oc >> 5, d = oc & 31;
                    outp[(((long)b_*NH_ + head)*NW + n)*DH + d] = f2b(v);
                }
            }
        }
    }
}

// ---------------------------------------------------------------------------
// pproj_ln2 v2: out-proj + window-reverse + unshift + residual + LN2.
// x1 kept in REGISTERS -> 19.5 KB static LDS, high occupancy.
// ---------------------------------------------------------------------------
__global__ __launch_bounds__(384)
void pproj_ln2(const bf16* __restrict__ A, const short* __restrict__ wf,
               const float* __restrict__ bias, const float* __restrict__ res,
               const float* __restrict__ g2, const float* __restrict__ b2,
               bf16* __restrict__ x1o, bf16* __restrict__ xno,
               const bf16* __restrict__ Ab, const short* __restrict__ wfB,
               const float* __restrict__ biasB, const float* __restrict__ resB,
               const float* __restrict__ g2B, const float* __restrict__ b2B,
               bf16* __restrict__ x1oB, bf16* __restrict__ xnoB,
               int nxblk)
{
    __shared__ short AsFp[2][8][64][8];   // 16384 B
    __shared__ float part[128][3][2];     //  3072 B

    int tid = threadIdx.x;
    int wid = tid >> 6, lane = tid & 63;
    int wr = (wid >= 3) ? 1 : 0, wc = wid - wr*3;
    int l15 = lane & 15, g = lane >> 4;

    int bx = blockIdx.x;
    const bf16* Ap = A; const short* wfp = wf; const float* biasp = bias;
    const float* resp = res; const float* g2p = g2; const float* b2p = b2;
    bf16* x1p = x1o; bf16* xnp = xno;
    if (bx >= nxblk) {
        bx -= nxblk; Ap = Ab; wfp = wfB; biasp = biasB; resp = resB;
        g2p = g2B; b2p = b2B; x1p = x1oB; xnp = xnoB;
    }
    int row0 = bx * 128;

    f32x4 acc[4][4];
    #pragma unroll
    for (int m = 0; m < 4; m++)
        #pragma unroll
        for (int n = 0; n < 4; n++)
            acc[m][n] = (f32x4){0.f,0.f,0.f,0.f};

    #define PSTAGE(buf_, k0_) {                                                  \
        int colk = (k0_) + (g << 3);                                             \
        if (wid < 6)                                                             \
            gload16(Ap + (long)(row0 + wid*16 + l15)*C_DIM + colk,               \
                    &AsFp[buf_][wid][0][0]);                                     \
        if (wid < 2)                                                             \
            gload16(Ap + (long)(row0 + (6+wid)*16 + l15)*C_DIM + colk,           \
                    &AsFp[buf_][6+wid][0][0]);                                   \
    }

    PSTAGE(0, 0);
    __syncthreads();
    for (int t = 0; t < 6; ++t) {
        int buf = t & 1;
        if (t + 1 < 6) PSTAGE(buf ^ 1, (t+1) << 5);
        short8 af[4], bf4[4];
        #pragma unroll
        for (int m = 0; m < 4; m++)
            af[m] = *((short8*)&AsFp[buf][wr*4 + m][lane][0]);
        const short* wbase = wfp + (((long)t*12 + wc*4)*64 + lane)*8;
        #pragma unroll
        for (int n = 0; n < 4; n++) bf4[n] = *(const short8*)(wbase + n*512);
        #pragma unroll
        for (int m = 0; m < 4; m++)
            #pragma unroll
            for (int n = 0; n < 4; n++)
                acc[m][n] = __builtin_amdgcn_mfma_f32_16x16x32_bf16(af[m], bf4[n], acc[m][n], 0, 0, 0);
        __syncthreads();
    }
    #undef PSTAGE

    float bias4[4], g24[4], b24[4];
    #pragma unroll
    for (int n2 = 0; n2 < 4; n2++) {
        int oc = wc*64 + n2*16 + l15;
        bias4[n2] = biasp[oc]; g24[n2] = g2p[oc]; b24[n2] = b2p[oc];
    }

    int gtv[4][4];
    #pragma unroll
    for (int m = 0; m < 4; m++) {
        #pragma unroll
        for (int rr = 0; rr < 4; rr++) {
            int t = row0 + wr*64 + m*16 + g*4 + rr;
            int b_ = t / NW, n = t - b_*NW;
            int w = b_ & (NWIN-1), b = b_ >> 6;
            int hs = (w >> 3)*WS_ + n/WS_;
            int wsf = (w & 7)*WS_ + n % WS_;
            int h = hs + SS_;  if (h >= HH)  h -= HH;
            int wc2 = wsf + SS_; if (wc2 >= WW2) wc2 -= WW2;
            int gt = b*L_TOK + h*WW2 + wc2;
            gtv[m][rr] = gt;
            int lrow = wr*64 + m*16 + g*4 + rr;
            float ps = 0.f, pss = 0.f;
            #pragma unroll
            for (int n2 = 0; n2 < 4; n2++) {
                int oc = wc*64 + n2*16 + l15;
                float x1 = resp[(long)gt*C_DIM + oc] + acc[m][n2][rr] + bias4[n2];
                acc[m][n2][rr] = x1;
                x1p[(long)gt*C_DIM + oc] = f2b(x1);
                ps += x1; pss += x1*x1;
            }
            ps  += __shfl_xor(ps, 1);  pss += __shfl_xor(pss, 1);
            ps  += __shfl_xor(ps, 2);  pss += __shfl_xor(pss, 2);
            ps  += __shfl_xor(ps, 4);  pss += __shfl_xor(pss, 4);
            ps  += __shfl_xor(ps, 8);  pss += __shfl_xor(pss, 8);
            if (l15 == 0) {
                part[lrow][wc][0] = ps;
                part[lrow][wc][1] = pss;
            }
        }
    }
    __syncthreads();

    #pragma unroll
    for (int m = 0; m < 4; m++) {
        #pragma unroll
        for (int rr = 0; rr < 4; rr++) {
            int lrow = wr*64 + m*16 + g*4 + rr;
            int gt = gtv[m][rr];
            float s  = part[lrow][0][0] + part[lrow][1][0] + part[lrow][2][0];
            float ss = part[lrow][0][1] + part[lrow][1][1] + part[lrow][2][1];
            float mean = s * (1.0f/192.0f);
            float var  = ss * (1.0f/192.0f) - mean*mean;
            float rstd = rsqrtf(var + 1e-5f);
            #pragma unroll
            for (int n2 = 0; n2 < 4; n2++) {
                int oc = wc*64 + n2*16 + l15;
                xnp[(long)gt*C_DIM + oc] = f2b((acc[m][n2][rr] - mean)*rstd*g24[n2] + b24[n2]);
            }
        }
    }
}

// ---------------------------------------------------------------------------
// mlp_fused4: per 64-token tile x stream; A-fragments read DIRECTLY from
// global (row-major == frag layout, L2-hot) -> NO xnF staging. LDS is only
// the double-buffered hid slice: 49,152 B -> 3 blocks/CU.
// ---------------------------------------------------------------------------
__global__ __launch_bounds__(384)
void mlp_fused4(const bf16* __restrict__ xn, const short* __restrict__ w1f,
                const short* __restrict__ w2f,
                const float* __restrict__ b1, const float* __restrict__ b2,
                const bf16* __restrict__ x1, float* __restrict__ dout,
                const bf16* __restrict__ xnB, const short* __restrict__ w1B,
                const short* __restrict__ w2B,
                const float* __restrict__ b1B, const float* __restrict__ b2B,
                const bf16* __restrict__ x1B, float* __restrict__ doutB,
                int nxblk)
{
    __shared__ short hidS[2][24*512];   // 49,152 B

    int tid = threadIdx.x;
    int wv = tid >> 6, lane = tid & 63;
    int l15 = lane & 15, g = lane >> 4;

    int bx = blockIdx.x;
    const bf16* xnp = xn; const short* w1p = w1f; const short* w2p = w2f;
    const float* b1p = b1; const float* b2p = b2;
    const bf16* x1p = x1; float* doutp = dout;
    if (bx >= nxblk) {
        bx -= nxblk; xnp = xnB; w1p = w1B; w2p = w2B; b1p = b1B; b2p = b2B;
        x1p = x1B; doutp = doutB;
    }
    int row0 = bx * 64;
    const bf16* abase = xnp + (long)(row0 + l15)*C_DIM + 8*g;   // + m*16*C_DIM + kb*32

    f32x4 ad[4][2], au[4][2];
    #pragma unroll
    for (int m = 0; m < 4; m++)
        #pragma unroll
        for (int n = 0; n < 2; n++)
            ad[m][n] = (f32x4){0.f,0.f,0.f,0.f};

    #define UP_SLICE(s_) {                                                       \
        _Pragma("unroll")                                                        \
        for (int m = 0; m < 4; m++)                                              \
            _Pragma("unroll")                                                    \
            for (int n = 0; n < 2; n++)                                          \
                au[m][n] = (f32x4){0.f,0.f,0.f,0.f};                             \
        _Pragma("unroll")                                                        \
        for (int kb = 0; kb < 6; ++kb) {                                         \
            short8 af[4];                                                        \
            _Pragma("unroll")                                                    \
            for (int m = 0; m < 4; m++)                                          \
                af[m] = *(const short8*)(abase + (long)m*16*C_DIM + kb*32);      \
            _Pragma("unroll")                                                    \
            for (int n = 0; n < 2; n++) {                                        \
                short8 bfv = *(const short8*)(w1p + (((long)kb*48 + 12*(s_) + 2*wv + n)*64 + lane)*8); \
                _Pragma("unroll")                                                \
                for (int m = 0; m < 4; m++)                                      \
                    au[m][n] = __builtin_amdgcn_mfma_f32_16x16x32_bf16(af[m], bfv, au[m][n], 0, 0, 0); \
            }                                                                    \
        }                                                                        \
    }

    #define SCATTER(s_, buf_) {                                                  \
        _Pragma("unroll")                                                        \
        for (int n = 0; n < 2; n++) {                                            \
            int hc = 32*wv + 16*n + l15;                                         \
            float bb = b1p[192*(s_) + hc];                                       \
            int kb2 = hc >> 5;                                                   \
            int Lhi = 16 * ((hc >> 3) & 3);                                      \
            int j = hc & 7;                                                      \
            _Pragma("unroll")                                                    \
            for (int m = 0; m < 4; m++) {                                        \
                _Pragma("unroll")                                                \
                for (int rr = 0; rr < 4; rr++) {                                 \
                    float v = au[m][n][rr] + bb;                                 \
                    float gl = 0.5f * v * (1.0f + erff(v * 0.70710678118654752f)); \
                    int L = (4*g + rr) + Lhi;                                    \
                    hidS[buf_][(m*6 + kb2)*512 + L*8 + j] = f2bs(gl);            \
                }                                                                \
            }                                                                    \
        }                                                                        \
    }

    #define DOWN_SLICE(s_, buf_) {                                               \
        _Pragma("unroll")                                                        \
        for (int kb = 0; kb < 6; ++kb) {                                         \
            short8 hf[4];                                                        \
            _Pragma("unroll")                                                    \
            for (int m = 0; m < 4; m++)                                          \
                hf[m] = *(short8*)(&hidS[buf_][(m*6 + kb)*512] + lane*8);        \
            _Pragma("unroll")                                                    \
            for (int n = 0; n < 2; n++) {                                        \
                short8 bfv = *(const short8*)(w2p + ((((long)(6*(s_) + kb))*12 + 2*wv + n)*64 + lane)*8); \
                _Pragma("unroll")                                                \
                for (int m = 0; m < 4; m++)                                      \
                    ad[m][n] = __builtin_amdgcn_mfma_f32_16x16x32_bf16(hf[m], bfv, ad[m][n], 0, 0, 0); \
            }                                                                    \
        }                                                                        \
    }

    UP_SLICE(0);
    SCATTER(0, 0);
    __syncthreads();
    UP_SLICE(1);
    DOWN_SLICE(0, 0);
    SCATTER(1, 1);
    __syncthreads();
    UP_SLICE(2);
    DOWN_SLICE(1, 1);
    SCATTER(2, 0);
    __syncthreads();
    UP_SLICE(3);
    DOWN_SLICE(2, 0);
    SCATTER(3, 1);
    __syncthreads();
    DOWN_SLICE(3, 1);

    #undef UP_SLICE
    #undef SCATTER
    #undef DOWN_SLICE

    // epilogue: + bias2 + x1 -> fp32 dout
    #pragma unroll
    for (int m = 0; m < 4; m++) {
        #pragma unroll
        for (int rr = 0; rr < 4; rr++) {
            int t = row0 + 16*m + 4*g + rr;
            long goff = (long)t*C_DIM;
            #pragma unroll
            for (int n = 0; n < 2; n++) {
                int oc = 32*wv + 16*n + l15;
                float v = ad[m][n][rr] + b2p[oc];
                doutp[goff + oc] = b2f(x1p[goff + oc]) + v;
            }
        }
    }
}

// ---------------------------------------------------------------------------
// mgemm fallback (fp32 weights from global): 128x64 tile, 4 waves.
// ---------------------------------------------------------------------------
#define BM 128
#define BN 64

template<int MODE>
__global__ __launch_bounds__(256)
void mgemm(const bf16* __restrict__ A1, const bf16* __restrict__ A2, int K1, int K,
           const float* __restrict__ W, const float* __restrict__ bias, int Nn,
           bf16* __restrict__ out, bf16* __restrict__ out2,
           const float* __restrict__ res_src, const bf16* __restrict__ prj,
           int t0, float* __restrict__ dout)
{
    __shared__ short AsF[8][64][8];
    __shared__ short BsF[4][64][8];
    int tid  = threadIdx.x;
    int wid  = tid >> 6, lane = tid & 63;
    int wr   = wid >> 1, wc = wid & 1;
    int row0 = blockIdx.x * BM, col0 = blockIdx.y * BN;

    f32x4 acc[4][2];
    #pragma unroll
    for (int m = 0; m < 4; m++)
        #pragma unroll
        for (int n = 0; n < 2; n++)
            acc[m][n] = (f32x4){0.f, 0.f, 0.f, 0.f};

    int ar = tid >> 2, akseg = tid & 3;
    int bc = tid & 63, bk8 = tid >> 6;

    for (int k0 = 0; k0 < K; k0 += 32) {
        {
            int col = k0 + akseg*8;
            const bf16* asrc = (col < K1) ? A1 : A2;
            int akc = (col < K1) ? col : col - K1;
            #pragma unroll
            for (int rr = 0; rr < 2; rr++) {
                int r = ar + rr*64;
                short8 av = *(const short8*)(asrc + (long)(row0 + r)*K1 + akc);
                *((short8*)&AsF[r >> 4][(r & 15) + (akseg << 4)][0]) = av;
            }
        }
        {
            short8 bv;
            #pragma unroll
            for (int j = 0; j < 8; j++)
                bv[j] = f2bs(W[(long)(k0 + bk8*8 + j)*Nn + col0 + bc]);
            *((short8*)&BsF[bc >> 4][(bc & 15) + (bk8 << 4)][0]) = bv;
        }
        __syncthreads();
        short8 af[4], bfr[2];
        #pragma unroll
        for (int m = 0; m < 4; m++) af[m]  = *((short8*)&AsF[wr*4 + m][lane][0]);
        #pragma unroll
        for (int n = 0; n < 2; n++) bfr[n] = *((short8*)&BsF[wc*2 + n][lane][0]);
        #pragma unroll
        for (int m = 0; m < 4; m++)
            #pragma unroll
            for (int n = 0; n < 2; n++)
                acc[m][n] = __builtin_amdgcn_mfma_f32_16x16x32_bf16(af[m], bfr[n], acc[m][n], 0, 0, 0);
        __syncthreads();
    }

    #pragma unroll
    for (int m = 0; m < 4; m++) {
        #pragma unroll
        for (int rr = 0; rr < 4; rr++) {
            int t = row0 + wr*64 + m*16 + (lane >> 4)*4 + rr;
            if (MODE == 4) {
                int tg = t0 + t;
                int b = tg / L_TOK, l = tg % L_TOK;
                int h = l / WW2, wcol = l % WW2;
                int hp = h - SS_;    if (hp < 0) hp += HH;
                int wp = wcol - SS_; if (wp < 0) wp += WW2;
                int b_ = b*NWIN + (hp/WS_)*8 + (wp/WS_);
                int n  = (hp%WS_)*WS_ + (wp%WS_);
                long wsoff = ((long)b_*NW + n)*C_DIM;
                long goff  = (long)tg*C_DIM;
                #pragma unroll
                for (int n2 = 0; n2 < 2; n2++) {
                    int oc = col0 + wc*32 + n2*16 + (lane & 15);
                    float v = acc[m][n2][rr] + bias[oc];
                    dout[goff + oc] = res_src[goff + oc] + b2f(prj[wsoff + oc]) + v;
                }
            } else {
                #pragma unroll
                for (int n2 = 0; n2 < 2; n2++) {
                    int oc = col0 + wc*32 + n2*16 + (lane & 15);
                    float v = acc[m][n2][rr] + bias[oc];
                    if (MODE == 0) {
                        out[(long)t*Nn + oc] = f2b(v);
                    } else if (MODE == 1) {
                        int b_ = t / NW, n = t % NW;
                        if (oc < C_DIM) {
                            int head = oc >> 5, d = oc & 31;
                            out[(((long)b_*NH_ + head)*NW + n)*DH + d] = f2b(v * 0.17677669529663687f);
                        } else {
                            int och = oc - C_DIM;
                            int head = och >> 5, d = och & 31;
                            out2[(((long)b_*NH_ + head)*NW + n)*DH + d] = f2b(v);
                        }
                    } else if (MODE == 2) {
                        int b_ = t / NW, n = t % NW;
                        int head = oc >> 5, d = oc & 31;
                        out[(((long)b_*NH_ + head)*NW + n)*DH + d] = f2b(v);
                    } else {
                        float g2 = 0.5f * v * (1.0f + erff(v * 0.70710678118654752f));
                        out[(long)t*Nn + oc] = f2b(g2);
                    }
                }
            }
        }
    }
}

// ---------------------------------------------------------------------------
// MFMA attention: 1 wave per (window,head), 2 waves/block.
// ---------------------------------------------------------------------------
#define PSTR 72
#define VSTR 72

__global__ __launch_bounds__(128)
void attn_mfma(const bf16* __restrict__ qb, const bf16* __restrict__ kb,
               const bf16* __restrict__ vse, const bf16* __restrict__ vde,
               const float* __restrict__ rpb,
               bf16* __restrict__ ose, bf16* __restrict__ ode)
{
    __shared__ float rpbs[169*NH_];
    __shared__ short P[2][64][PSTR];
    __shared__ short VTs[2][32][VSTR];
    __shared__ short VTd[2][32][VSTR];
    int tid = threadIdx.x, wid = tid >> 6, lane = tid & 63;
    for (int i = tid; i < 169*NH_; i += 128) rpbs[i] = rpb[i];
    __syncthreads();

    int bh = blockIdx.x*2 + wid;
    int b_ = bh / NH_, head = bh % NH_;
    int w = b_ & (NWIN-1);
    int wh = w >> 3, ww = w & 7;
    long base = (long)bh * (NW*DH);
    int l15 = lane & 15, g = lane >> 4;
    int j0 = lane >> 2, seg = lane & 3;

    short8 qf[4], kf[4], va_[4], vb_[4];
    #pragma unroll
    for (int mi = 0; mi < 4; mi++) {
        int r = l15 + 16*mi; if (r > 48) r = 48;
        qf[mi] = *(const short8*)(qb + base + r*DH + 8*g);
    }
    #pragma unroll
    for (int ni = 0; ni < 4; ni++) {
        int r = l15 + 16*ni; if (r > 48) r = 48;
        kf[ni] = *(const short8*)(kb + base + r*DH + 8*g);
    }
    #pragma unroll
    for (int it = 0; it < 4; ++it) {
        int j = j0 + 16*it;
        va_[it] = (short8){0,0,0,0,0,0,0,0};
        vb_[it] = (short8){0,0,0,0,0,0,0,0};
        if (j < NW) {
            va_[it] = *(const short8*)(vse + base + j*DH + seg*8);
            vb_[it] = *(const short8*)(vde + base + j*DH + seg*8);
        }
    }

    f32x4 sA[4][4];
    #pragma unroll
    for (int mi = 0; mi < 4; mi++)
        #pragma unroll
        for (int ni = 0; ni < 4; ni++)
            sA[mi][ni] = (f32x4){0.f,0.f,0.f,0.f};
    #pragma unroll
    for (int mi = 0; mi < 4; mi++)
        #pragma unroll
        for (int ni = 0; ni < 4; ni++)
            sA[mi][ni] = __builtin_amdgcn_mfma_f32_16x16x32_bf16(qf[mi], kf[ni], sA[mi][ni], 0, 0, 0);

    #pragma unroll
    for (int it = 0; it < 4; ++it) {
        int j = j0 + 16*it;
        #pragma unroll
        for (int s2 = 0; s2 < 8; ++s2) {
            VTs[wid][seg*8 + s2][j] = va_[it][s2];
            VTd[wid][seg*8 + s2][j] = vb_[it][s2];
        }
    }

    int jv[4], j7r_[4], j7c_[4], jrh_[4], jrc_[4];
    #pragma unroll
    for (int ni = 0; ni < 4; ++ni) {
        int j = 16*ni + l15;
        jv[ni] = (j < NW);
        int a = (j*37) >> 8; int c = j - 7*a;
        j7r_[ni] = a; j7c_[ni] = c;
        int jh = wh*7 + a, jw = ww*7 + c;
        jrh_[ni] = (jh >= 49) + (jh >= 53);
        jrc_[ni] = (jw >= 49) + (jw >= 53);
    }

    #pragma unroll
    for (int mi = 0; mi < 4; mi++) {
        #pragma unroll
        for (int rr = 0; rr < 4; rr++) {
            int i = 16*mi + 4*g + rr;
            int iv = (i < NW);
            int i7r = (i*37) >> 8; int i7c = i - 7*i7r;
            int ih = wh*7 + i7r, iw = ww*7 + i7c;
            int irh = (ih >= 49) + (ih >= 53), irc = (iw >= 49) + (iw >= 53);
            float e[4], sum = 0.f;
            #pragma unroll
            for (int ni = 0; ni < 4; ni++) {
                float sv;
                if (iv && jv[ni]) {
                    int ri = (i7r - j7r_[ni] + 6)*13 + (i7c - j7c_[ni] + 6);
                    float msk = (irh == jrh_[ni] && irc == jrc_[ni]) ? 0.f : -100.f;
                    sv = sA[mi][ni][rr] + rpbs[ri*NH_ + head] + msk;
                } else {
                    sv = -1e30f;
                }
                e[ni] = __expf(sv); sum += e[ni];
            }
            sum += __shfl_xor(sum, 1);
            sum += __shfl_xor(sum, 2);
            sum += __shfl_xor(sum, 4);
            sum += __shfl_xor(sum, 8);
            float inv = 1.0f / sum;
            #pragma unroll
            for (int ni = 0; ni < 4; ni++)
                P[wid][i][16*ni + l15] = f2bs(e[ni] * inv);
        }
    }
    __syncthreads();

    f32x4 o1[4][2], o2[4][2];
    #pragma unroll
    for (int mi = 0; mi < 4; mi++)
        #pragma unroll
        for (int di = 0; di < 2; di++) {
            o1[mi][di] = (f32x4){0.f,0.f,0.f,0.f};
            o2[mi][di] = (f32x4){0.f,0.f,0.f,0.f};
        }
    #pragma unroll
    for (int mi = 0; mi < 4; mi++) {
        #pragma unroll
        for (int kk = 0; kk < 2; kk++) {
            short8 ap = *((short8*)&P[wid][16*mi + l15][kk*32 + 8*g]);
            #pragma unroll
            for (int di = 0; di < 2; di++) {
                short8 bv1 = *((short8*)&VTs[wid][16*di + l15][kk*32 + 8*g]);
                o1[mi][di] = __builtin_amdgcn_mfma_f32_16x16x32_bf16(ap, bv1, o1[mi][di], 0, 0, 0);
                short8 bv2 = *((short8*)&VTd[wid][16*di + l15][kk*32 + 8*g]);
                o2[mi][di] = __builtin_amdgcn_mfma_f32_16x16x32_bf16(ap, bv2, o2[mi][di], 0, 0, 0);
            }
        }
    }

    #pragma unroll
    for (int mi = 0; mi < 4; mi++) {
        #pragma unroll
        for (int rr = 0; rr < 4; rr++) {
            int i = 16*mi + 4*g + rr;
            if (i < NW) {
                long ob = ((long)b_*NW + i)*C_DIM + head*DH;
                #pragma unroll
                for (int di = 0; di < 2; di++) {
                    ose[ob + 16*di + l15] = f2b(o1[mi][di][rr]);
                    ode[ob + 16*di + l15] = f2b(o2[mi][di][rr]);
                }
            }
        }
    }
}

// ---------------------------------------------------------------------------
// resid_ln2 (fallback path only)
// ---------------------------------------------------------------------------
__global__ void resid_ln2_kernel(const float* __restrict__ se, const float* __restrict__ de,
                                 const bf16* __restrict__ pse, const bf16* __restrict__ pde,
                                 const float* __restrict__ g2s, const float* __restrict__ bb2s,
                                 const float* __restrict__ g2d, const float* __restrict__ bb2d,
                                 bf16* __restrict__ xns, bf16* __restrict__ xnd)
{
    int t = blockIdx.x, tid = threadIdx.x;
    int b = t / L_TOK, l = t % L_TOK;
    int h = l / WW2, wc = l % WW2;
    int hp = h - SS_;  if (hp < 0) hp += HH;
    int wp = wc - SS_; if (wp < 0) wp += WW2;
    int b_ = b*NWIN + (hp/WS_)*8 + (wp/WS_);
    int n  = (hp%WS_)*WS_ + (wp%WS_);
    long wsoff = ((long)b_*NW + n)*C_DIM;
    long off   = (long)t*C_DIM;
    {
        float x0 = se[off+tid]     + b2f(pse[wsoff+tid]);
        float x1 = se[off+tid+64]  + b2f(pse[wsoff+tid+64]);
        float x2 = se[off+tid+128] + b2f(pse[wsoff+tid+128]);
        float s  = wave_sum64(x0+x1+x2);
        float ss = wave_sum64(x0*x0 + x1*x1 + x2*x2);
        float mean = s * (1.0f/192.0f);
        float var  = ss * (1.0f/192.0f) - mean*mean;
        float rstd = rsqrtf(var + 1e-5f);
        xns[off+tid]     = f2b((x0-mean)*rstd*g2s[tid]     + bb2s[tid]);
        xns[off+tid+64]  = f2b((x1-mean)*rstd*g2s[tid+64]  + bb2s[tid+64]);
        xns[off+tid+128] = f2b((x2-mean)*rstd*g2s[tid+128] + bb2s[tid+128]);
    }
    {
        float x0 = de[off+tid]     + b2f(pde[wsoff+tid]);
        float x1 = de[off+tid+64]  + b2f(pde[wsoff+tid+64]);
        float x2 = de[off+tid+128] + b2f(pde[wsoff+tid+128]);
        float s  = wave_sum64(x0+x1+x2);
        float ss = wave_sum64(x0*x0 + x1*x1 + x2*x2);
        float mean = s * (1.0f/192.0f);
        float var  = ss * (1.0f/192.0f) - mean*mean;
        float rstd = rsqrtf(var + 1e-5f);
        xnd[off+tid]     = f2b((x0-mean)*rstd*g2d[tid]     + bb2d[tid]);
        xnd[off+tid+64]  = f2b((x1-mean)*rstd*g2d[tid+64]  + bb2d[tid+64]);
        xnd[off+tid+128] = f2b((x2-mean)*rstd*g2d[tid+128] + bb2d[tid+128]);
    }
}

// ---------------------------------------------------------------------------
extern "C" void kernel_launch(void* const* d_in, const int* in_sizes, int n_in,
                              void* d_out, int out_size, void* d_ws, size_t ws_size,
                              hipStream_t stream)
{
    const float* se     = (const float*)d_in[0];
    const float* de     = (const float*)d_in[1];
    const float* co     = (const float*)d_in[2];
    const float* n1se_g = (const float*)d_in[4];
    const float* n1se_b = (const float*)d_in[5];
    const float* n1de_g = (const float*)d_in[6];
    const float* n1de_b = (const float*)d_in[7];
    const float* rpb    = (const float*)d_in[8];
    const float* vse_w  = (const float*)d_in[9];
    const float* vse_b  = (const float*)d_in[10];
    const float* vde_w  = (const float*)d_in[11];
    const float* vde_b  = (const float*)d_in[12];
    const float* qk_w   = (const float*)d_in[13];
    const float* qk_b   = (const float*)d_in[14];
    const float* pse_w  = (const float*)d_in[15];
    const float* pse_b  = (const float*)d_in[16];
    const float* pde_w  = (const float*)d_in[17];
    const float* pde_b  = (const float*)d_in[18];
    const float* n2se_g = (const float*)d_in[19];
    const float* n2se_b = (const float*)d_in[20];
    const float* n2de_g = (const float*)d_in[21];
    const float* n2de_b = (const float*)d_in[22];
    const float* mse_w1 = (const float*)d_in[23];
    const float* mse_b1 = (const float*)d_in[24];
    const float* mse_w2 = (const float*)d_in[25];
    const float* mse_b2 = (const float*)d_in[26];
    const float* mde_w1 = (const float*)d_in[27];
    const float* mde_b1 = (const float*)d_in[28];
    const float* mde_w2 = (const float*)d_in[29];
    const float* mde_b2 = (const float*)d_in[30];

    char* ws = (char*)d_ws;
    const size_t U = (size_t)TOK * C_DIM * 2;   // 19,267,584 bytes
    bf16* sw   = (bf16*)(ws + 0*U);
    bf16* dw   = (bf16*)(ws + 1*U);
    bf16* cw   = (bf16*)(ws + 2*U);
    bf16* vse  = (bf16*)(ws + 3*U);
    bf16* vde  = (bf16*)(ws + 4*U);
    bf16* ode  = (bf16*)(ws + 5*U);
    bf16* qb   = (bf16*)(ws + 0*U);
    bf16* kb   = (bf16*)(ws + 1*U);
    bf16* ose  = (bf16*)(ws + 2*U);
    bf16* x1se = (bf16*)(ws + 0*U);
    bf16* x1de = (bf16*)(ws + 1*U);
    bf16* xns  = (bf16*)(ws + 3*U);
    bf16* xnd  = (bf16*)(ws + 4*U);
    // fallback slots
    bf16* fb_pse = (bf16*)(ws + 0*U);
    bf16* fb_pde = (bf16*)(ws + 1*U);
    bf16* fb_xns = (bf16*)(ws + 2*U);
    bf16* fb_xnd = (bf16*)(ws + 3*U);
    bf16* fb_hid = (bf16*)(ws + 4*U);
    short* wfb = (short*)(ws + 6*U);            // 884,736 bf16 = 1.73 MB

    const bool frag = (ws_size >= 6*U + 884736ull*2ull);
    float* dout = (float*)d_out;
    const int CH = TOK/2;
    const int NX = TOK/128;   // 392

    if (frag)
        wconv<<<dim3(72, 9), 256, 0, stream>>>(vse_w, vde_w, qk_w, pse_w, pde_w,
                                               mse_w1, mse_w2, mde_w1, mde_w2, wfb);
    prep_kernel<<<TOK, 64, 0, stream>>>(se, de, co, n1se_g, n1se_b, n1de_g, n1de_b, sw, dw, cw);

    if (frag) {
        fgemm2<2,true,8><<<dim3(NX*2, 1), 384, 0, stream>>>(sw, cw, C_DIM, 2*C_DIM, wfb + 0, vse_b, C_DIM,
                                                            vse, nullptr,
                                                            dw, cw, wfb + 73728, vde_b, vde, NX);
        fgemm2<1,false,8><<<dim3(NX, 2), 384, 0, stream>>>(cw, cw, C_DIM, C_DIM, wfb + 147456, qk_b, 384,
                                                           qb, kb,
                                                           nullptr, nullptr, nullptr, nullptr, nullptr, 0);
    } else {
        mgemm<2><<<dim3(TOK/BM, C_DIM/BN), 256, 0, stream>>>(sw, cw, C_DIM, 2*C_DIM, vse_w, vse_b, C_DIM,
                                                             vse, nullptr, nullptr, nullptr, 0, nullptr);
        mgemm<2><<<dim3(TOK/BM, C_DIM/BN), 256, 0, stream>>>(dw, cw, C_DIM, 2*C_DIM, vde_w, vde_b, C_DIM,
                                                             vde, nullptr, nullptr, nullptr, 0, nullptr);
        mgemm<1><<<dim3(TOK/BM, 384/BN), 256, 0, stream>>>(cw, cw, C_DIM, C_DIM, qk_w, qk_b, 384,
                                                           qb, kb, nullptr, nullptr, 0, nullptr);
    }

    attn_mfma<<<BWIN*NH_/2, 128, 0, stream>>>(qb, kb, vse, vde, rpb, ose, ode);

    if (frag) {
        pproj_ln2<<<dim3(NX*2, 1), 384, 0, stream>>>(ose, wfb + 221184, pse_b, se, n2se_g, n2se_b,
                                                     x1se, xns,
                                                     ode, wfb + 258048, pde_b, de, n2de_g, n2de_b,
                                                     x1de, xnd, NX);
        mlp_fused4<<<dim3((TOK/64)*2, 1), 384, 0, stream>>>(xns, wfb + 294912, wfb + 442368,
                                                            mse_b1, mse_b2, x1se, dout,
                                                            xnd, wfb + 589824, wfb + 737280,
                                                            mde_b1, mde_b2, x1de,
                                                            dout + (size_t)TOK*C_DIM, TOK/64);
    } else {
        mgemm<0><<<dim3(TOK/BM, C_DIM/BN), 256, 0, stream>>>(ose, ose, C_DIM, C_DIM, pse_w, pse_b, C_DIM,
                                                             fb_pse, nullptr, nullptr, nullptr, 0, nullptr);
        mgemm<0><<<dim3(TOK/BM, C_DIM/BN), 256, 0, stream>>>(ode, ode, C_DIM, C_DIM, pde_w, pde_b, C_DIM,
                                                             fb_pde, nullptr, nullptr, nullptr, 0, nullptr);
        resid_ln2_kernel<<<TOK, 64, 0, stream>>>(se, de, fb_pse, fb_pde,
                                                 n2se_g, n2se_b, n2de_g, n2de_b, fb_xns, fb_xnd);
        for (int c0 = 0; c0 < 2; c0++) {
            int t0 = c0 * CH;
            mgemm<3><<<dim3(CH/BM, HID_/BN), 256, 0, stream>>>(fb_xns + (long)t0*C_DIM, fb_xns + (long)t0*C_DIM,
                                                               C_DIM, C_DIM, mse_w1, mse_b1, HID_,
                                                               fb_hid, nullptr, nullptr, nullptr, 0, nullptr);
            mgemm<4><<<dim3(CH/BM, C_DIM/BN), 256, 0, stream>>>(fb_hid, fb_hid, HID_, HID_, mse_w2, mse_b2, C_DIM,
                                                                nullptr, nullptr, se, fb_pse, t0, dout);
        }
        for (int c0 = 0; c0 < 2; c0++) {
            int t0 = c0 * CH;
            mgemm<3><<<dim3(CH/BM, HID_/BN), 256, 0, stream>>>(fb_xnd + (long)t0*C_DIM, fb_xnd + (long)t0*C_DIM,
                                                               C_DIM, C_DIM, mde_w1, mde_b1, HID_,
                                                               fb_hid, nullptr, nullptr, nullptr, 0, nullptr);
            mgemm<4><<<dim3(CH/BM, C_DIM/BN), 256, 0, stream>>>(fb_hid, fb_hid, HID_, HID_, mde_w2, mde_b2, C_DIM,
                                                                nullptr, nullptr, de, fb_pde, t0,
                                                                dout + (size_t)TOK*C_DIM);
        }
    }
}

// Round 14
// 368.144 us; speedup vs baseline: 1.3108x; 1.3108x over previous
//
#include <hip/hip_runtime.h>
#include <hip/hip_bf16.h>
#include <math.h>
#include <stdint.h>

typedef __hip_bfloat16 bf16;
typedef __attribute__((ext_vector_type(8))) short short8;
typedef __attribute__((ext_vector_type(4))) float f32x4;

#define B_SZ   16
#define HH     56
#define WW2    56
#define L_TOK  3136
#define C_DIM  192
#define NH_    6
#define DH     32
#define WS_    7
#define SS_    3
#define NW     49
#define NWIN   64
#define BWIN   (B_SZ*NWIN)  // 1024
#define TOK    (BWIN*NW)    // 50176
#define HID_   768

__device__ __forceinline__ float b2f(bf16 x){ return __bfloat162float(x); }
__device__ __forceinline__ bf16  f2b(float x){ return __float2bfloat16(x); }
__device__ __forceinline__ short f2bs(float x){ bf16 h = __float2bfloat16(x); return *reinterpret_cast<short*>(&h); }

// async global->LDS, 16B per lane; LDS dest = wave-uniform base + lane*16
__device__ __forceinline__ void gload16(const void* g, void* l) {
    __builtin_amdgcn_global_load_lds(
        (const __attribute__((address_space(1))) void*)(uintptr_t)g,
        (__attribute__((address_space(3))) void*)(uintptr_t)l, 16, 0, 0);
}

__device__ __forceinline__ float wave_sum64(float v){
    #pragma unroll
    for (int off = 32; off > 0; off >>= 1) v += __shfl_xor(v, off, 64);
    return v;
}

// ---------------------------------------------------------------------------
// LN1(se), LN1(de), copy(co) + cyclic shift + window partition.
// ---------------------------------------------------------------------------
__global__ void prep_kernel(const float* __restrict__ se, const float* __restrict__ de,
                            const float* __restrict__ co,
                            const float* __restrict__ g1s, const float* __restrict__ b1s,
                            const float* __restrict__ g1d, const float* __restrict__ b1d,
                            bf16* __restrict__ sw, bf16* __restrict__ dw, bf16* __restrict__ cw)
{
    int t   = blockIdx.x;
    int tid = threadIdx.x;
    int b_  = t / NW, n = t % NW;
    int b   = b_ / NWIN, w = b_ % NWIN;
    int wh  = w >> 3, wwi = w & 7;
    int i   = n / WS_, j = n % WS_;
    int hs  = wh*WS_ + i, ws = wwi*WS_ + j;
    int hsrc = hs + SS_; if (hsrc >= HH)  hsrc -= HH;
    int wsrc = ws + SS_; if (wsrc >= WW2) wsrc -= WW2;
    long src = ((long)(b*L_TOK + hsrc*WW2 + wsrc)) * C_DIM;
    long dst = (long)t * C_DIM;

    {
        float x0 = se[src+tid], x1 = se[src+tid+64], x2 = se[src+tid+128];
        float s  = wave_sum64(x0+x1+x2);
        float ss = wave_sum64(x0*x0 + x1*x1 + x2*x2);
        float mean = s * (1.0f/192.0f);
        float var  = ss * (1.0f/192.0f) - mean*mean;
        float rstd = rsqrtf(var + 1e-5f);
        sw[dst+tid]     = f2b((x0-mean)*rstd*g1s[tid]     + b1s[tid]);
        sw[dst+tid+64]  = f2b((x1-mean)*rstd*g1s[tid+64]  + b1s[tid+64]);
        sw[dst+tid+128] = f2b((x2-mean)*rstd*g1s[tid+128] + b1s[tid+128]);
    }
    {
        float x0 = de[src+tid], x1 = de[src+tid+64], x2 = de[src+tid+128];
        float s  = wave_sum64(x0+x1+x2);
        float ss = wave_sum64(x0*x0 + x1*x1 + x2*x2);
        float mean = s * (1.0f/192.0f);
        float var  = ss * (1.0f/192.0f) - mean*mean;
        float rstd = rsqrtf(var + 1e-5f);
        dw[dst+tid]     = f2b((x0-mean)*rstd*g1d[tid]     + b1d[tid]);
        dw[dst+tid+64]  = f2b((x1-mean)*rstd*g1d[tid+64]  + b1d[tid+64]);
        dw[dst+tid+128] = f2b((x2-mean)*rstd*g1d[tid+128] + b1d[tid+128]);
    }
    cw[dst+tid]     = f2b(co[src+tid]);
    cw[dst+tid+64]  = f2b(co[src+tid+64]);
    cw[dst+tid+128] = f2b(co[src+tid+128]);
}

// ---------------------------------------------------------------------------
// Weight pre-convert: fp32 [K][N] -> bf16 MFMA-B-fragment order.
// ---------------------------------------------------------------------------
__global__ __launch_bounds__(256)
void wconv(const float* w0,const float* w1,const float* w2,const float* w3,const float* w4,
           const float* w5,const float* w6,const float* w7,const float* w8, short* dst)
{
    const float* src; int K, N; long doff;
    switch (blockIdx.y) {
      case 0: src=w0; K=384; N=192; doff=0;      break;
      case 1: src=w1; K=384; N=192; doff=73728;  break;
      case 2: src=w2; K=192; N=384; doff=147456; break;
      case 3: src=w3; K=192; N=192; doff=221184; break;
      case 4: src=w4; K=192; N=192; doff=258048; break;
      case 5: src=w5; K=192; N=768; doff=294912; break;
      case 6: src=w6; K=768; N=192; doff=442368; break;
      case 7: src=w7; K=192; N=768; doff=589824; break;
      default:src=w8; K=768; N=192; doff=737280; break;
    }
    int nblk = (K>>5)*(N>>6);
    int bid = blockIdx.x;
    if (bid >= nblk) return;
    int kb = bid / (N>>6), nb = bid % (N>>6);
    __shared__ float tile[32][65];
    int tid = threadIdx.x;
    #pragma unroll
    for (int it = 0; it < 8; ++it) {
        int idx = tid + it*256;
        int r = idx >> 6, c = idx & 63;
        tile[r][c] = src[(long)(kb*32 + r)*N + nb*64 + c];
    }
    __syncthreads();
    int lane = tid & 63, nl = tid >> 6;
    short8 v;
    #pragma unroll
    for (int j = 0; j < 8; ++j)
        v[j] = f2bs(tile[(lane>>4)*8 + j][nl*16 + (lane&15)]);
    long nig = (long)nb*4 + nl;
    *(short8*)(dst + doff + (((long)kb*(N>>4) + nig)*64 + lane)*8) = v;
}

// ---------------------------------------------------------------------------
// fgemm2: C = A(bf16) @ Wfrag(bf16) + bias. MR16 16-row slices per tile.
// MODE 0 plain / 1 qk-scatter / 2 v-scatter
// ---------------------------------------------------------------------------
template<int MODE, bool DUAL, int MR16>
__global__ __launch_bounds__(384)
void fgemm2(const bf16* __restrict__ A1, const bf16* __restrict__ A2, int K1, int K,
            const short* __restrict__ wf, const float* __restrict__ bias, int Nn,
            bf16* __restrict__ out, bf16* __restrict__ out2,
            const bf16* __restrict__ A1b, const bf16* __restrict__ A2b,
            const short* __restrict__ wfB, const float* __restrict__ biasB,
            bf16* __restrict__ outB, int nxblk)
{
    __shared__ short AsF[2][MR16][64][8];
    const int MROWS = MR16 * 16;
    const int MPW   = MR16 / 2;
    int tid = threadIdx.x;
    int wid = tid >> 6, lane = tid & 63;
    int wr = (wid >= 3) ? 1 : 0, wc = wid - wr*3;
    int l15 = lane & 15, g = lane >> 4;

    int bx = blockIdx.x;
    const bf16 *A1p = A1, *A2p = A2; const short* wfp = wf;
    const float* biasp = bias; bf16* outp = out;
    if (DUAL && bx >= nxblk) {
        bx -= nxblk; A1p = A1b; A2p = A2b; wfp = wfB; biasp = biasB; outp = outB;
    }
    int row0 = bx * MROWS, col0 = blockIdx.y * 192;
    const int ntiles = Nn >> 4;

    f32x4 acc[MPW][4];
    #pragma unroll
    for (int m = 0; m < MPW; m++)
        #pragma unroll
        for (int n = 0; n < 4; n++)
            acc[m][n] = (f32x4){0.f,0.f,0.f,0.f};

    int nk = K >> 5;
    #define STAGE(buf_, k0_) {                                                   \
        int colk = (k0_) + (g << 3);                                             \
        const bf16* asrc = (colk < K1) ? A1p : A2p;                              \
        int kc = (colk < K1) ? colk : colk - K1;                                 \
        if (wid < MR16)                                                          \
            gload16(asrc + (long)(row0 + wid*16 + l15)*K1 + kc,                  \
                    &AsF[buf_][wid][0][0]);                                      \
        if (MR16 == 8 && wid < 2)                                                \
            gload16(asrc + (long)(row0 + (6+wid)*16 + l15)*K1 + kc,              \
                    &AsF[buf_][(MR16==8 ? 6+wid : 0)][0][0]);                    \
    }

    STAGE(0, 0);
    __syncthreads();
    for (int t = 0; t < nk; ++t) {
        int buf = t & 1;
        if (t + 1 < nk) STAGE(buf ^ 1, (t+1) << 5);
        short8 af[MPW], bf4[4];
        #pragma unroll
        for (int m = 0; m < MPW; m++) af[m] = *((short8*)&AsF[buf][wr*MPW + m][lane][0]);
        const short* wbase = wfp + (((long)t*ntiles + (col0>>4) + wc*4)*64 + lane)*8;
        #pragma unroll
        for (int n = 0; n < 4; n++) bf4[n] = *(const short8*)(wbase + n*512);
        __builtin_amdgcn_s_setprio(1);
        #pragma unroll
        for (int m = 0; m < MPW; m++)
            #pragma unroll
            for (int n = 0; n < 4; n++)
                acc[m][n] = __builtin_amdgcn_mfma_f32_16x16x32_bf16(af[m], bf4[n], acc[m][n], 0, 0, 0);
        __builtin_amdgcn_s_setprio(0);
        __syncthreads();
    }
    #undef STAGE

    #pragma unroll
    for (int m = 0; m < MPW; m++) {
        #pragma unroll
        for (int rr = 0; rr < 4; rr++) {
            int t = row0 + wr*(MROWS/2) + m*16 + g*4 + rr;
            #pragma unroll
            for (int n2 = 0; n2 < 4; n2++) {
                int oc = col0 + wc*64 + n2*16 + l15;
                float v = acc[m][n2][rr] + biasp[oc];
                if (MODE == 0) {
                    outp[(long)t*Nn + oc] = f2b(v);
                } else if (MODE == 1) {
                    int b_ = t / NW, n = t % NW;
                    if (oc < C_DIM) {
                        int head = oc >> 5, d = oc & 31;
                        outp[(((long)b_*NH_ + head)*NW + n)*DH + d] = f2b(v * 0.17677669529663687f);
                    } else {
                        int och = oc - C_DIM;
                        int head = och >> 5, d = och & 31;
                        out2[(((long)b_*NH_ + head)*NW + n)*DH + d] = f2b(v);
                    }
                } else { // MODE 2
                    int b_ = t / NW, n = t % NW;
                    int head = oc >> 5, d = oc & 31;
                    outp[(((long)b_*NH_ + head)*NW + n)*DH + d] = f2b(v);
                }
            }
        }
    }
}

// ---------------------------------------------------------------------------
// pproj_ln2 v2: out-proj + window-reverse + unshift + residual + LN2.
// x1 kept in REGISTERS -> 19.5 KB static LDS, high occupancy.
// ---------------------------------------------------------------------------
__global__ __launch_bounds__(384)
void pproj_ln2(const bf16* __restrict__ A, const short* __restrict__ wf,
               const float* __restrict__ bias, const float* __restrict__ res,
               const float* __restrict__ g2, const float* __restrict__ b2,
               bf16* __restrict__ x1o, bf16* __restrict__ xno,
               const bf16* __restrict__ Ab, const short* __restrict__ wfB,
               const float* __restrict__ biasB, const float* __restrict__ resB,
               const float* __restrict__ g2B, const float* __restrict__ b2B,
               bf16* __restrict__ x1oB, bf16* __restrict__ xnoB,
               int nxblk)
{
    __shared__ short AsFp[2][8][64][8];   // 16384 B
    __shared__ float part[128][3][2];     //  3072 B

    int tid = threadIdx.x;
    int wid = tid >> 6, lane = tid & 63;
    int wr = (wid >= 3) ? 1 : 0, wc = wid - wr*3;
    int l15 = lane & 15, g = lane >> 4;

    int bx = blockIdx.x;
    const bf16* Ap = A; const short* wfp = wf; const float* biasp = bias;
    const float* resp = res; const float* g2p = g2; const float* b2p = b2;
    bf16* x1p = x1o; bf16* xnp = xno;
    if (bx >= nxblk) {
        bx -= nxblk; Ap = Ab; wfp = wfB; biasp = biasB; resp = resB;
        g2p = g2B; b2p = b2B; x1p = x1oB; xnp = xnoB;
    }
    int row0 = bx * 128;

    f32x4 acc[4][4];
    #pragma unroll
    for (int m = 0; m < 4; m++)
        #pragma unroll
        for (int n = 0; n < 4; n++)
            acc[m][n] = (f32x4){0.f,0.f,0.f,0.f};

    #define PSTAGE(buf_, k0_) {                                                  \
        int colk = (k0_) + (g << 3);                                             \
        if (wid < 6)                                                             \
            gload16(Ap + (long)(row0 + wid*16 + l15)*C_DIM + colk,               \
                    &AsFp[buf_][wid][0][0]);                                     \
        if (wid < 2)                                                             \
            gload16(Ap + (long)(row0 + (6+wid)*16 + l15)*C_DIM + colk,           \
                    &AsFp[buf_][6+wid][0][0]);                                   \
    }

    PSTAGE(0, 0);
    __syncthreads();
    for (int t = 0; t < 6; ++t) {
        int buf = t & 1;
        if (t + 1 < 6) PSTAGE(buf ^ 1, (t+1) << 5);
        short8 af[4], bf4[4];
        #pragma unroll
        for (int m = 0; m < 4; m++)
            af[m] = *((short8*)&AsFp[buf][wr*4 + m][lane][0]);
        const short* wbase = wfp + (((long)t*12 + wc*4)*64 + lane)*8;
        #pragma unroll
        for (int n = 0; n < 4; n++) bf4[n] = *(const short8*)(wbase + n*512);
        __builtin_amdgcn_s_setprio(1);
        #pragma unroll
        for (int m = 0; m < 4; m++)
            #pragma unroll
            for (int n = 0; n < 4; n++)
                acc[m][n] = __builtin_amdgcn_mfma_f32_16x16x32_bf16(af[m], bf4[n], acc[m][n], 0, 0, 0);
        __builtin_amdgcn_s_setprio(0);
        __syncthreads();
    }
    #undef PSTAGE

    float bias4[4], g24[4], b24[4];
    #pragma unroll
    for (int n2 = 0; n2 < 4; n2++) {
        int oc = wc*64 + n2*16 + l15;
        bias4[n2] = biasp[oc]; g24[n2] = g2p[oc]; b24[n2] = b2p[oc];
    }

    int gtv[4][4];
    #pragma unroll
    for (int m = 0; m < 4; m++) {
        #pragma unroll
        for (int rr = 0; rr < 4; rr++) {
            int t = row0 + wr*64 + m*16 + g*4 + rr;
            int b_ = t / NW, n = t - b_*NW;
            int w = b_ & (NWIN-1), b = b_ >> 6;
            int hs = (w >> 3)*WS_ + n/WS_;
            int wsf = (w & 7)*WS_ + n % WS_;
            int h = hs + SS_;  if (h >= HH)  h -= HH;
            int wc2 = wsf + SS_; if (wc2 >= WW2) wc2 -= WW2;
            int gt = b*L_TOK + h*WW2 + wc2;
            gtv[m][rr] = gt;
            int lrow = wr*64 + m*16 + g*4 + rr;
            float ps = 0.f, pss = 0.f;
            #pragma unroll
            for (int n2 = 0; n2 < 4; n2++) {
                int oc = wc*64 + n2*16 + l15;
                float x1 = resp[(long)gt*C_DIM + oc] + acc[m][n2][rr] + bias4[n2];
                acc[m][n2][rr] = x1;
                x1p[(long)gt*C_DIM + oc] = f2b(x1);
                ps += x1; pss += x1*x1;
            }
            ps  += __shfl_xor(ps, 1);  pss += __shfl_xor(pss, 1);
            ps  += __shfl_xor(ps, 2);  pss += __shfl_xor(pss, 2);
            ps  += __shfl_xor(ps, 4);  pss += __shfl_xor(pss, 4);
            ps  += __shfl_xor(ps, 8);  pss += __shfl_xor(pss, 8);
            if (l15 == 0) {
                part[lrow][wc][0] = ps;
                part[lrow][wc][1] = pss;
            }
        }
    }
    __syncthreads();

    #pragma unroll
    for (int m = 0; m < 4; m++) {
        #pragma unroll
        for (int rr = 0; rr < 4; rr++) {
            int lrow = wr*64 + m*16 + g*4 + rr;
            int gt = gtv[m][rr];
            float s  = part[lrow][0][0] + part[lrow][1][0] + part[lrow][2][0];
            float ss = part[lrow][0][1] + part[lrow][1][1] + part[lrow][2][1];
            float mean = s * (1.0f/192.0f);
            float var  = ss * (1.0f/192.0f) - mean*mean;
            float rstd = rsqrtf(var + 1e-5f);
            #pragma unroll
            for (int n2 = 0; n2 < 4; n2++) {
                int oc = wc*64 + n2*16 + l15;
                xnp[(long)gt*C_DIM + oc] = f2b((acc[m][n2][rr] - mean)*rstd*g24[n2] + b24[n2]);
            }
        }
    }
}

// ---------------------------------------------------------------------------
// mlp_fused5: per 64-token tile x stream, up->GELU->down; hid sliced into
// 8 x 96-col slices, DOUBLE-BUFFERED (hidS[2] = 24.6 KB). LDS total
// 49,152 B -> 3 blocks/CU (18 waves). up(s)||down(s-1) per interval + T5.
// ---------------------------------------------------------------------------
__global__ __launch_bounds__(384)
void mlp_fused5(const bf16* __restrict__ xn, const short* __restrict__ w1f,
                const short* __restrict__ w2f,
                const float* __restrict__ b1, const float* __restrict__ b2,
                const bf16* __restrict__ x1, float* __restrict__ dout,
                const bf16* __restrict__ xnB, const short* __restrict__ w1B,
                const short* __restrict__ w2B,
                const float* __restrict__ b1B, const float* __restrict__ b2B,
                const bf16* __restrict__ x1B, float* __restrict__ doutB,
                int nxblk)
{
    __shared__ short xnF[24*512];       // 24,576 B (4 mtile x 6 kb)
    __shared__ short hidS[2][12*512];   // 24,576 B (2 x 96-col slice, A-frag)

    int tid = threadIdx.x;
    int wv = tid >> 6, lane = tid & 63;
    int l15 = lane & 15, g = lane >> 4;

    int bx = blockIdx.x;
    const bf16* xnp = xn; const short* w1p = w1f; const short* w2p = w2f;
    const float* b1p = b1; const float* b2p = b2;
    const bf16* x1p = x1; float* doutp = dout;
    if (bx >= nxblk) {
        bx -= nxblk; xnp = xnB; w1p = w1B; w2p = w2B; b1p = b1B; b2p = b2B;
        x1p = x1B; doutp = doutB;
    }
    int row0 = bx * 64;

    // stage xn tile 64x192 -> A-frag order
    #pragma unroll
    for (int p = 0; p < 4; ++p) {
        int pp = wv*4 + p;
        int a = pp / 6, kb = pp % 6;
        gload16(xnp + (long)(row0 + 16*a + l15)*C_DIM + 32*kb + 8*g,
                xnF + (a*6 + kb)*512);
    }
    __syncthreads();

    f32x4 ad[4][2];
    f32x4 au[4];          // per slice: this wave's 16 hid cols
    #pragma unroll
    for (int m = 0; m < 4; m++)
        #pragma unroll
        for (int n = 0; n < 2; n++)
            ad[m][n] = (f32x4){0.f,0.f,0.f,0.f};

    // UP slice s: wave owns hid cols [96s+16wv, 96s+16wv+16); ntile = 6s+wv
    #define UP_SLICE(s_) {                                                       \
        _Pragma("unroll")                                                        \
        for (int m = 0; m < 4; m++) au[m] = (f32x4){0.f,0.f,0.f,0.f};            \
        _Pragma("unroll")                                                        \
        for (int kb = 0; kb < 6; ++kb) {                                         \
            short8 bfv = *(const short8*)(w1p + (((long)kb*48 + 6*(s_) + wv)*64 + lane)*8); \
            __builtin_amdgcn_s_setprio(1);                                       \
            _Pragma("unroll")                                                    \
            for (int m = 0; m < 4; m++) {                                        \
                short8 af = *(short8*)(xnF + (m*6 + kb)*512 + lane*8);           \
                au[m] = __builtin_amdgcn_mfma_f32_16x16x32_bf16(af, bfv, au[m], 0, 0, 0); \
            }                                                                    \
            __builtin_amdgcn_s_setprio(0);                                       \
        }                                                                        \
    }

    // SCATTER slice s into hidS[buf] (A-frag order within 96-col slice)
    #define SCATTER(s_, buf_) {                                                  \
        int hc = 16*wv + l15;                                                    \
        float bb = b1p[96*(s_) + hc];                                            \
        int kb2 = hc >> 5;                                                       \
        int Lhi = 16 * ((hc >> 3) & 3);                                          \
        int j = hc & 7;                                                          \
        _Pragma("unroll")                                                        \
        for (int m = 0; m < 4; m++) {                                            \
            _Pragma("unroll")                                                    \
            for (int rr = 0; rr < 4; rr++) {                                     \
                float v = au[m][rr] + bb;                                        \
                float gl = 0.5f * v * (1.0f + erff(v * 0.70710678118654752f));   \
                int L = (4*g + rr) + Lhi;                                        \
                hidS[buf_][(m*3 + kb2)*512 + L*8 + j] = f2bs(gl);                \
            }                                                                    \
        }                                                                        \
    }

    // DOWN slice s: accumulate out cols [32wv, 32wv+32) over 3 k-blocks
    #define DOWN_SLICE(s_, buf_) {                                               \
        _Pragma("unroll")                                                        \
        for (int kb = 0; kb < 3; ++kb) {                                         \
            short8 hf[4];                                                        \
            _Pragma("unroll")                                                    \
            for (int m = 0; m < 4; m++)                                          \
                hf[m] = *(short8*)(&hidS[buf_][(m*3 + kb)*512] + lane*8);        \
            __builtin_amdgcn_s_setprio(1);                                       \
            _Pragma("unroll")                                                    \
            for (int n = 0; n < 2; n++) {                                        \
                short8 bfv = *(const short8*)(w2p + ((((long)(3*(s_) + kb))*12 + 2*wv + n)*64 + lane)*8); \
                _Pragma("unroll")                                                \
                for (int m = 0; m < 4; m++)                                      \
                    ad[m][n] = __builtin_amdgcn_mfma_f32_16x16x32_bf16(hf[m], bfv, ad[m][n], 0, 0, 0); \
            }                                                                    \
            __builtin_amdgcn_s_setprio(0);                                       \
        }                                                                        \
    }

    UP_SLICE(0);
    SCATTER(0, 0);
    __syncthreads();
    for (int s = 1; s < 8; ++s) {
        UP_SLICE(s);
        DOWN_SLICE(s-1, (s-1)&1);
        SCATTER(s, s&1);
        __syncthreads();
    }
    DOWN_SLICE(7, 1);

    #undef UP_SLICE
    #undef SCATTER
    #undef DOWN_SLICE

    // epilogue: + bias2 + x1 -> fp32 dout
    #pragma unroll
    for (int m = 0; m < 4; m++) {
        #pragma unroll
        for (int rr = 0; rr < 4; rr++) {
            int t = row0 + 16*m + 4*g + rr;
            long goff = (long)t*C_DIM;
            #pragma unroll
            for (int n = 0; n < 2; n++) {
                int oc = 32*wv + 16*n + l15;
                float v = ad[m][n][rr] + b2p[oc];
                doutp[goff + oc] = b2f(x1p[goff + oc]) + v;
            }
        }
    }
}

// ---------------------------------------------------------------------------
// mgemm fallback (fp32 weights from global): 128x64 tile, 4 waves.
// ---------------------------------------------------------------------------
#define BM 128
#define BN 64

template<int MODE>
__global__ __launch_bounds__(256)
void mgemm(const bf16* __restrict__ A1, const bf16* __restrict__ A2, int K1, int K,
           const float* __restrict__ W, const float* __restrict__ bias, int Nn,
           bf16* __restrict__ out, bf16* __restrict__ out2,
           const float* __restrict__ res_src, const bf16* __restrict__ prj,
           int t0, float* __restrict__ dout)
{
    __shared__ short AsF[8][64][8];
    __shared__ short BsF[4][64][8];
    int tid  = threadIdx.x;
    int wid  = tid >> 6, lane = tid & 63;
    int wr   = wid >> 1, wc = wid & 1;
    int row0 = blockIdx.x * BM, col0 = blockIdx.y * BN;

    f32x4 acc[4][2];
    #pragma unroll
    for (int m = 0; m < 4; m++)
        #pragma unroll
        for (int n = 0; n < 2; n++)
            acc[m][n] = (f32x4){0.f, 0.f, 0.f, 0.f};

    int ar = tid >> 2, akseg = tid & 3;
    int bc = tid & 63, bk8 = tid >> 6;

    for (int k0 = 0; k0 < K; k0 += 32) {
        {
            int col = k0 + akseg*8;
            const bf16* asrc = (col < K1) ? A1 : A2;
            int akc = (col < K1) ? col : col - K1;
            #pragma unroll
            for (int rr = 0; rr < 2; rr++) {
                int r = ar + rr*64;
                short8 av = *(const short8*)(asrc + (long)(row0 + r)*K1 + akc);
                *((short8*)&AsF[r >> 4][(r & 15) + (akseg << 4)][0]) = av;
            }
        }
        {
            short8 bv;
            #pragma unroll
            for (int j = 0; j < 8; j++)
                bv[j] = f2bs(W[(long)(k0 + bk8*8 + j)*Nn + col0 + bc]);
            *((short8*)&BsF[bc >> 4][(bc & 15) + (bk8 << 4)][0]) = bv;
        }
        __syncthreads();
        short8 af[4], bfr[2];
        #pragma unroll
        for (int m = 0; m < 4; m++) af[m]  = *((short8*)&AsF[wr*4 + m][lane][0]);
        #pragma unroll
        for (int n = 0; n < 2; n++) bfr[n] = *((short8*)&BsF[wc*2 + n][lane][0]);
        #pragma unroll
        for (int m = 0; m < 4; m++)
            #pragma unroll
            for (int n = 0; n < 2; n++)
                acc[m][n] = __builtin_amdgcn_mfma_f32_16x16x32_bf16(af[m], bfr[n], acc[m][n], 0, 0, 0);
        __syncthreads();
    }

    #pragma unroll
    for (int m = 0; m < 4; m++) {
        #pragma unroll
        for (int rr = 0; rr < 4; rr++) {
            int t = row0 + wr*64 + m*16 + (lane >> 4)*4 + rr;
            if (MODE == 4) {
                int tg = t0 + t;
                int b = tg / L_TOK, l = tg % L_TOK;
                int h = l / WW2, wcol = l % WW2;
                int hp = h - SS_;    if (hp < 0) hp += HH;
                int wp = wcol - SS_; if (wp < 0) wp += WW2;
                int b_ = b*NWIN + (hp/WS_)*8 + (wp/WS_);
                int n  = (hp%WS_)*WS_ + (wp%WS_);
                long wsoff = ((long)b_*NW + n)*C_DIM;
                long goff  = (long)tg*C_DIM;
                #pragma unroll
                for (int n2 = 0; n2 < 2; n2++) {
                    int oc = col0 + wc*32 + n2*16 + (lane & 15);
                    float v = acc[m][n2][rr] + bias[oc];
                    dout[goff + oc] = res_src[goff + oc] + b2f(prj[wsoff + oc]) + v;
                }
            } else {
                #pragma unroll
                for (int n2 = 0; n2 < 2; n2++) {
                    int oc = col0 + wc*32 + n2*16 + (lane & 15);
                    float v = acc[m][n2][rr] + bias[oc];
                    if (MODE == 0) {
                        out[(long)t*Nn + oc] = f2b(v);
                    } else if (MODE == 1) {
                        int b_ = t / NW, n = t % NW;
                        if (oc < C_DIM) {
                            int head = oc >> 5, d = oc & 31;
                            out[(((long)b_*NH_ + head)*NW + n)*DH + d] = f2b(v * 0.17677669529663687f);
                        } else {
                            int och = oc - C_DIM;
                            int head = och >> 5, d = och & 31;
                            out2[(((long)b_*NH_ + head)*NW + n)*DH + d] = f2b(v);
                        }
                    } else if (MODE == 2) {
                        int b_ = t / NW, n = t % NW;
                        int head = oc >> 5, d = oc & 31;
                        out[(((long)b_*NH_ + head)*NW + n)*DH + d] = f2b(v);
                    } else {
                        float g2 = 0.5f * v * (1.0f + erff(v * 0.70710678118654752f));
                        out[(long)t*Nn + oc] = f2b(g2);
                    }
                }
            }
        }
    }
}

// ---------------------------------------------------------------------------
// MFMA attention: 1 wave per (window,head), 2 waves/block.
// ---------------------------------------------------------------------------
#define PSTR 72
#define VSTR 72

__global__ __launch_bounds__(128)
void attn_mfma(const bf16* __restrict__ qb, const bf16* __restrict__ kb,
               const bf16* __restrict__ vse, const bf16* __restrict__ vde,
               const float* __restrict__ rpb,
               bf16* __restrict__ ose, bf16* __restrict__ ode)
{
    __shared__ float rpbs[169*NH_];
    __shared__ short P[2][64][PSTR];
    __shared__ short VTs[2][32][VSTR];
    __shared__ short VTd[2][32][VSTR];
    int tid = threadIdx.x, wid = tid >> 6, lane = tid & 63;
    for (int i = tid; i < 169*NH_; i += 128) rpbs[i] = rpb[i];
    __syncthreads();

    int bh = blockIdx.x*2 + wid;
    int b_ = bh / NH_, head = bh % NH_;
    int w = b_ & (NWIN-1);
    int wh = w >> 3, ww = w & 7;
    long base = (long)bh * (NW*DH);
    int l15 = lane & 15, g = lane >> 4;
    int j0 = lane >> 2, seg = lane & 3;

    short8 qf[4], kf[4], va_[4], vb_[4];
    #pragma unroll
    for (int mi = 0; mi < 4; mi++) {
        int r = l15 + 16*mi; if (r > 48) r = 48;
        qf[mi] = *(const short8*)(qb + base + r*DH + 8*g);
    }
    #pragma unroll
    for (int ni = 0; ni < 4; ni++) {
        int r = l15 + 16*ni; if (r > 48) r = 48;
        kf[ni] = *(const short8*)(kb + base + r*DH + 8*g);
    }
    #pragma unroll
    for (int it = 0; it < 4; ++it) {
        int j = j0 + 16*it;
        va_[it] = (short8){0,0,0,0,0,0,0,0};
        vb_[it] = (short8){0,0,0,0,0,0,0,0};
        if (j < NW) {
            va_[it] = *(const short8*)(vse + base + j*DH + seg*8);
            vb_[it] = *(const short8*)(vde + base + j*DH + seg*8);
        }
    }

    f32x4 sA[4][4];
    #pragma unroll
    for (int mi = 0; mi < 4; mi++)
        #pragma unroll
        for (int ni = 0; ni < 4; ni++)
            sA[mi][ni] = (f32x4){0.f,0.f,0.f,0.f};
    #pragma unroll
    for (int mi = 0; mi < 4; mi++)
        #pragma unroll
        for (int ni = 0; ni < 4; ni++)
            sA[mi][ni] = __builtin_amdgcn_mfma_f32_16x16x32_bf16(qf[mi], kf[ni], sA[mi][ni], 0, 0, 0);

    #pragma unroll
    for (int it = 0; it < 4; ++it) {
        int j = j0 + 16*it;
        #pragma unroll
        for (int s2 = 0; s2 < 8; ++s2) {
            VTs[wid][seg*8 + s2][j] = va_[it][s2];
            VTd[wid][seg*8 + s2][j] = vb_[it][s2];
        }
    }

    int jv[4], j7r_[4], j7c_[4], jrh_[4], jrc_[4];
    #pragma unroll
    for (int ni = 0; ni < 4; ++ni) {
        int j = 16*ni + l15;
        jv[ni] = (j < NW);
        int a = (j*37) >> 8; int c = j - 7*a;
        j7r_[ni] = a; j7c_[ni] = c;
        int jh = wh*7 + a, jw = ww*7 + c;
        jrh_[ni] = (jh >= 49) + (jh >= 53);
        jrc_[ni] = (jw >= 49) + (jw >= 53);
    }

    #pragma unroll
    for (int mi = 0; mi < 4; mi++) {
        #pragma unroll
        for (int rr = 0; rr < 4; rr++) {
            int i = 16*mi + 4*g + rr;
            int iv = (i < NW);
            int i7r = (i*37) >> 8; int i7c = i - 7*i7r;
            int ih = wh*7 + i7r, iw = ww*7 + i7c;
            int irh = (ih >= 49) + (ih >= 53), irc = (iw >= 49) + (iw >= 53);
            float e[4], sum = 0.f;
            #pragma unroll
            for (int ni = 0; ni < 4; ni++) {
                float sv;
                if (iv && jv[ni]) {
                    int ri = (i7r - j7r_[ni] + 6)*13 + (i7c - j7c_[ni] + 6);
                    float msk = (irh == jrh_[ni] && irc == jrc_[ni]) ? 0.f : -100.f;
                    sv = sA[mi][ni][rr] + rpbs[ri*NH_ + head] + msk;
                } else {
                    sv = -1e30f;
                }
                e[ni] = __expf(sv); sum += e[ni];
            }
            sum += __shfl_xor(sum, 1);
            sum += __shfl_xor(sum, 2);
            sum += __shfl_xor(sum, 4);
            sum += __shfl_xor(sum, 8);
            float inv = 1.0f / sum;
            #pragma unroll
            for (int ni = 0; ni < 4; ni++)
                P[wid][i][16*ni + l15] = f2bs(e[ni] * inv);
        }
    }
    __syncthreads();

    f32x4 o1[4][2], o2[4][2];
    #pragma unroll
    for (int mi = 0; mi < 4; mi++)
        #pragma unroll
        for (int di = 0; di < 2; di++) {
            o1[mi][di] = (f32x4){0.f,0.f,0.f,0.f};
            o2[mi][di] = (f32x4){0.f,0.f,0.f,0.f};
        }
    #pragma unroll
    for (int mi = 0; mi < 4; mi++) {
        #pragma unroll
        for (int kk = 0; kk < 2; kk++) {
            short8 ap = *((short8*)&P[wid][16*mi + l15][kk*32 + 8*g]);
            #pragma unroll
            for (int di = 0; di < 2; di++) {
                short8 bv1 = *((short8*)&VTs[wid][16*di + l15][kk*32 + 8*g]);
                o1[mi][di] = __builtin_amdgcn_mfma_f32_16x16x32_bf16(ap, bv1, o1[mi][di], 0, 0, 0);
                short8 bv2 = *((short8*)&VTd[wid][16*di + l15][kk*32 + 8*g]);
                o2[mi][di] = __builtin_amdgcn_mfma_f32_16x16x32_bf16(ap, bv2, o2[mi][di], 0, 0, 0);
            }
        }
    }

    #pragma unroll
    for (int mi = 0; mi < 4; mi++) {
        #pragma unroll
        for (int rr = 0; rr < 4; rr++) {
            int i = 16*mi + 4*g + rr;
            if (i < NW) {
                long ob = ((long)b_*NW + i)*C_DIM + head*DH;
                #pragma unroll
                for (int di = 0; di < 2; di++) {
                    ose[ob + 16*di + l15] = f2b(o1[mi][di][rr]);
                    ode[ob + 16*di + l15] = f2b(o2[mi][di][rr]);
                }
            }
        }
    }
}

// ---------------------------------------------------------------------------
// resid_ln2 (fallback path only)
// ---------------------------------------------------------------------------
__global__ void resid_ln2_kernel(const float* __restrict__ se, const float* __restrict__ de,
                                 const bf16* __restrict__ pse, const bf16* __restrict__ pde,
                                 const float* __restrict__ g2s, const float* __restrict__ bb2s,
                                 const float* __restrict__ g2d, const float* __restrict__ bb2d,
                                 bf16* __restrict__ xns, bf16* __restrict__ xnd)
{
    int t = blockIdx.x, tid = threadIdx.x;
    int b = t / L_TOK, l = t % L_TOK;
    int h = l / WW2, wc = l % WW2;
    int hp = h - SS_;  if (hp < 0) hp += HH;
    int wp = wc - SS_; if (wp < 0) wp += WW2;
    int b_ = b*NWIN + (hp/WS_)*8 + (wp/WS_);
    int n  = (hp%WS_)*WS_ + (wp%WS_);
    long wsoff = ((long)b_*NW + n)*C_DIM;
    long off   = (long)t*C_DIM;
    {
        float x0 = se[off+tid]     + b2f(pse[wsoff+tid]);
        float x1 = se[off+tid+64]  + b2f(pse[wsoff+tid+64]);
        float x2 = se[off+tid+128] + b2f(pse[wsoff+tid+128]);
        float s  = wave_sum64(x0+x1+x2);
        float ss = wave_sum64(x0*x0 + x1*x1 + x2*x2);
        float mean = s * (1.0f/192.0f);
        float var  = ss * (1.0f/192.0f) - mean*mean;
        float rstd = rsqrtf(var + 1e-5f);
        xns[off+tid]     = f2b((x0-mean)*rstd*g2s[tid]     + bb2s[tid]);
        xns[off+tid+64]  = f2b((x1-mean)*rstd*g2s[tid+64]  + bb2s[tid+64]);
        xns[off+tid+128] = f2b((x2-mean)*rstd*g2s[tid+128] + bb2s[tid+128]);
    }
    {
        float x0 = de[off+tid]     + b2f(pde[wsoff+tid]);
        float x1 = de[off+tid+64]  + b2f(pde[wsoff+tid+64]);
        float x2 = de[off+tid+128] + b2f(pde[wsoff+tid+128]);
        float s  = wave_sum64(x0+x1+x2);
        float ss = wave_sum64(x0*x0 + x1*x1 + x2*x2);
        float mean = s * (1.0f/192.0f);
        float var  = ss * (1.0f/192.0f) - mean*mean;
        float rstd = rsqrtf(var + 1e-5f);
        xnd[off+tid]     = f2b((x0-mean)*rstd*g2d[tid]     + bb2d[tid]);
        xnd[off+tid+64]  = f2b((x1-mean)*rstd*g2d[tid+64]  + bb2d[tid+64]);
        xnd[off+tid+128] = f2b((x2-mean)*rstd*g2d[tid+128] + bb2d[tid+128]);
    }
}

// ---------------------------------------------------------------------------
extern "C" void kernel_launch(void* const* d_in, const int* in_sizes, int n_in,
                              void* d_out, int out_size, void* d_ws, size_t ws_size,
                              hipStream_t stream)
{
    const float* se     = (const float*)d_in[0];
    const float* de     = (const float*)d_in[1];
    const float* co     = (const float*)d_in[2];
    const float* n1se_g = (const float*)d_in[4];
    const float* n1se_b = (const float*)d_in[5];
    const float* n1de_g = (const float*)d_in[6];
    const float* n1de_b = (const float*)d_in[7];
    const float* rpb    = (const float*)d_in[8];
    const float* vse_w  = (const float*)d_in[9];
    const float* vse_b  = (const float*)d_in[10];
    const float* vde_w  = (const float*)d_in[11];
    const float* vde_b  = (const float*)d_in[12];
    const float* qk_w   = (const float*)d_in[13];
    const float* qk_b   = (const float*)d_in[14];
    const float* pse_w  = (const float*)d_in[15];
    const float* pse_b  = (const float*)d_in[16];
    const float* pde_w  = (const float*)d_in[17];
    const float* pde_b  = (const float*)d_in[18];
    const float* n2se_g = (const float*)d_in[19];
    const float* n2se_b = (const float*)d_in[20];
    const float* n2de_g = (const float*)d_in[21];
    const float* n2de_b = (const float*)d_in[22];
    const float* mse_w1 = (const float*)d_in[23];
    const float* mse_b1 = (const float*)d_in[24];
    const float* mse_w2 = (const float*)d_in[25];
    const float* mse_b2 = (const float*)d_in[26];
    const float* mde_w1 = (const float*)d_in[27];
    const float* mde_b1 = (const float*)d_in[28];
    const float* mde_w2 = (const float*)d_in[29];
    const float* mde_b2 = (const float*)d_in[30];

    char* ws = (char*)d_ws;
    const size_t U = (size_t)TOK * C_DIM * 2;   // 19,267,584 bytes
    bf16* sw   = (bf16*)(ws + 0*U);
    bf16* dw   = (bf16*)(ws + 1*U);
    bf16* cw   = (bf16*)(ws + 2*U);
    bf16* vse  = (bf16*)(ws + 3*U);
    bf16* vde  = (bf16*)(ws + 4*U);
    bf16* ode  = (bf16*)(ws + 5*U);
    bf16* qb   = (bf16*)(ws + 0*U);
    bf16* kb   = (bf16*)(ws + 1*U);
    bf16* ose  = (bf16*)(ws + 2*U);
    bf16* x1se = (bf16*)(ws + 0*U);
    bf16* x1de = (bf16*)(ws + 1*U);
    bf16* xns  = (bf16*)(ws + 3*U);
    bf16* xnd  = (bf16*)(ws + 4*U);
    // fallback slots
    bf16* fb_pse = (bf16*)(ws + 0*U);
    bf16* fb_pde = (bf16*)(ws + 1*U);
    bf16* fb_xns = (bf16*)(ws + 2*U);
    bf16* fb_xnd = (bf16*)(ws + 3*U);
    bf16* fb_hid = (bf16*)(ws + 4*U);
    short* wfb = (short*)(ws + 6*U);            // 884,736 bf16 = 1.73 MB

    const bool frag = (ws_size >= 6*U + 884736ull*2ull);
    float* dout = (float*)d_out;
    const int CH = TOK/2;
    const int NX = TOK/128;   // 392

    if (frag)
        wconv<<<dim3(72, 9), 256, 0, stream>>>(vse_w, vde_w, qk_w, pse_w, pde_w,
                                               mse_w1, mse_w2, mde_w1, mde_w2, wfb);
    prep_kernel<<<TOK, 64, 0, stream>>>(se, de, co, n1se_g, n1se_b, n1de_g, n1de_b, sw, dw, cw);

    if (frag) {
        fgemm2<2,true,8><<<dim3(NX*2, 1), 384, 0, stream>>>(sw, cw, C_DIM, 2*C_DIM, wfb + 0, vse_b, C_DIM,
                                                            vse, nullptr,
                                                            dw, cw, wfb + 73728, vde_b, vde, NX);
        fgemm2<1,false,8><<<dim3(NX, 2), 384, 0, stream>>>(cw, cw, C_DIM, C_DIM, wfb + 147456, qk_b, 384,
                                                           qb, kb,
                                                           nullptr, nullptr, nullptr, nullptr, nullptr, 0);
    } else {
        mgemm<2><<<dim3(TOK/BM, C_DIM/BN), 256, 0, stream>>>(sw, cw, C_DIM, 2*C_DIM, vse_w, vse_b, C_DIM,
                                                             vse, nullptr, nullptr, nullptr, 0, nullptr);
        mgemm<2><<<dim3(TOK/BM, C_DIM/BN), 256, 0, stream>>>(dw, cw, C_DIM, 2*C_DIM, vde_w, vde_b, C_DIM,
                                                             vde, nullptr, nullptr, nullptr, 0, nullptr);
        mgemm<1><<<dim3(TOK/BM, 384/BN), 256, 0, stream>>>(cw, cw, C_DIM, C_DIM, qk_w, qk_b, 384,
                                                           qb, kb, nullptr, nullptr, 0, nullptr);
    }

    attn_mfma<<<BWIN*NH_/2, 128, 0, stream>>>(qb, kb, vse, vde, rpb, ose, ode);

    if (frag) {
        pproj_ln2<<<dim3(NX*2, 1), 384, 0, stream>>>(ose, wfb + 221184, pse_b, se, n2se_g, n2se_b,
                                                     x1se, xns,
                                                     ode, wfb + 258048, pde_b, de, n2de_g, n2de_b,
                                                     x1de, xnd, NX);
        mlp_fused5<<<dim3((TOK/64)*2, 1), 384, 0, stream>>>(xns, wfb + 294912, wfb + 442368,
                                                            mse_b1, mse_b2, x1se, dout,
                                                            xnd, wfb + 589824, wfb + 737280,
                                                            mde_b1, mde_b2, x1de,
                                                            dout + (size_t)TOK*C_DIM, TOK/64);
    } else {
        mgemm<0><<<dim3(TOK/BM, C_DIM/BN), 256, 0, stream>>>(ose, ose, C_DIM, C_DIM, pse_w, pse_b, C_DIM,
                                                             fb_pse, nullptr, nullptr, nullptr, 0, nullptr);
        mgemm<0><<<dim3(TOK/BM, C_DIM/BN), 256, 0, stream>>>(ode, ode, C_DIM, C_DIM, pde_w, pde_b, C_DIM,
                                                             fb_pde, nullptr, nullptr, nullptr, 0, nullptr);
        resid_ln2_kernel<<<TOK, 64, 0, stream>>>(se, de, fb_pse, fb_pde,
                                                 n2se_g, n2se_b, n2de_g, n2de_b, fb_xns, fb_xnd);
        for (int c0 = 0; c0 < 2; c0++) {
            int t0 = c0 * CH;
            mgemm<3><<<dim3(CH/BM, HID_/BN), 256, 0, stream>>>(fb_xns + (long)t0*C_DIM, fb_xns + (long)t0*C_DIM,
                                                               C_DIM, C_DIM, mse_w1, mse_b1, HID_,
                                                               fb_hid, nullptr, nullptr, nullptr, 0, nullptr);
            mgemm<4><<<dim3(CH/BM, C_DIM/BN), 256, 0, stream>>>(fb_hid, fb_hid, HID_, HID_, mse_w2, mse_b2, C_DIM,
                                                                nullptr, nullptr, se, fb_pse, t0, dout);
        }
        for (int c0 = 0; c0 < 2; c0++) {
            int t0 = c0 * CH;
            mgemm<3><<<dim3(CH/BM, HID_/BN), 256, 0, stream>>>(fb_xnd + (long)t0*C_DIM, fb_xnd + (long)t0*C_DIM,
                                                               C_DIM, C_DIM, mde_w1, mde_b1, HID_,
                                                               fb_hid, nullptr, nullptr, nullptr, 0, nullptr);
            mgemm<4><<<dim3(CH/BM, C_DIM/BN), 256, 0, stream>>>(fb_hid, fb_hid, HID_, HID_, mde_w2, mde_b2, C_DIM,
                                                                nullptr, nullptr, de, fb_pde, t0,
                                                                dout + (size_t)TOK*C_DIM);
        }
    }
}

// Round 15
// 330.018 us; speedup vs baseline: 1.4623x; 1.1155x over previous
//
#include <hip/hip_runtime.h>
#include <hip/hip_bf16.h>
#include <math.h>
#include <stdint.h>

typedef __hip_bfloat16 bf16;
typedef __attribute__((ext_vector_type(8))) short short8;
typedef __attribute__((ext_vector_type(4))) float f32x4;

#define B_SZ   16
#define HH     56
#define WW2    56
#define L_TOK  3136
#define C_DIM  192
#define NH_    6
#define DH     32
#define WS_    7
#define SS_    3
#define NW     49
#define NWIN   64
#define BWIN   (B_SZ*NWIN)  // 1024
#define TOK    (BWIN*NW)    // 50176
#define HID_   768

__device__ __forceinline__ float b2f(bf16 x){ return __bfloat162float(x); }
__device__ __forceinline__ bf16  f2b(float x){ return __float2bfloat16(x); }
__device__ __forceinline__ short f2bs(float x){ bf16 h = __float2bfloat16(x); return *reinterpret_cast<short*>(&h); }

// async global->LDS, 16B per lane; LDS dest = wave-uniform base + lane*16
__device__ __forceinline__ void gload16(const void* g, void* l) {
    __builtin_amdgcn_global_load_lds(
        (const __attribute__((address_space(1))) void*)(uintptr_t)g,
        (__attribute__((address_space(3))) void*)(uintptr_t)l, 16, 0, 0);
}

__device__ __forceinline__ float wave_sum64(float v){
    #pragma unroll
    for (int off = 32; off > 0; off >>= 1) v += __shfl_xor(v, off, 64);
    return v;
}

// ---------------------------------------------------------------------------
// LN1(se), LN1(de), copy(co) + cyclic shift + window partition.
// ---------------------------------------------------------------------------
__global__ void prep_kernel(const float* __restrict__ se, const float* __restrict__ de,
                            const float* __restrict__ co,
                            const float* __restrict__ g1s, const float* __restrict__ b1s,
                            const float* __restrict__ g1d, const float* __restrict__ b1d,
                            bf16* __restrict__ sw, bf16* __restrict__ dw, bf16* __restrict__ cw)
{
    int t   = blockIdx.x;
    int tid = threadIdx.x;
    int b_  = t / NW, n = t % NW;
    int b   = b_ / NWIN, w = b_ % NWIN;
    int wh  = w >> 3, wwi = w & 7;
    int i   = n / WS_, j = n % WS_;
    int hs  = wh*WS_ + i, ws = wwi*WS_ + j;
    int hsrc = hs + SS_; if (hsrc >= HH)  hsrc -= HH;
    int wsrc = ws + SS_; if (wsrc >= WW2) wsrc -= WW2;
    long src = ((long)(b*L_TOK + hsrc*WW2 + wsrc)) * C_DIM;
    long dst = (long)t * C_DIM;

    {
        float x0 = se[src+tid], x1 = se[src+tid+64], x2 = se[src+tid+128];
        float s  = wave_sum64(x0+x1+x2);
        float ss = wave_sum64(x0*x0 + x1*x1 + x2*x2);
        float mean = s * (1.0f/192.0f);
        float var  = ss * (1.0f/192.0f) - mean*mean;
        float rstd = rsqrtf(var + 1e-5f);
        sw[dst+tid]     = f2b((x0-mean)*rstd*g1s[tid]     + b1s[tid]);
        sw[dst+tid+64]  = f2b((x1-mean)*rstd*g1s[tid+64]  + b1s[tid+64]);
        sw[dst+tid+128] = f2b((x2-mean)*rstd*g1s[tid+128] + b1s[tid+128]);
    }
    {
        float x0 = de[src+tid], x1 = de[src+tid+64], x2 = de[src+tid+128];
        float s  = wave_sum64(x0+x1+x2);
        float ss = wave_sum64(x0*x0 + x1*x1 + x2*x2);
        float mean = s * (1.0f/192.0f);
        float var  = ss * (1.0f/192.0f) - mean*mean;
        float rstd = rsqrtf(var + 1e-5f);
        dw[dst+tid]     = f2b((x0-mean)*rstd*g1d[tid]     + b1d[tid]);
        dw[dst+tid+64]  = f2b((x1-mean)*rstd*g1d[tid+64]  + b1d[tid+64]);
        dw[dst+tid+128] = f2b((x2-mean)*rstd*g1d[tid+128] + b1d[tid+128]);
    }
    cw[dst+tid]     = f2b(co[src+tid]);
    cw[dst+tid+64]  = f2b(co[src+tid+64]);
    cw[dst+tid+128] = f2b(co[src+tid+128]);
}

// ---------------------------------------------------------------------------
// Weight pre-convert: fp32 [K][N] -> bf16 MFMA-B-fragment order.
// ---------------------------------------------------------------------------
__global__ __launch_bounds__(256)
void wconv(const float* w0,const float* w1,const float* w2,const float* w3,const float* w4,
           const float* w5,const float* w6,const float* w7,const float* w8, short* dst)
{
    const float* src; int K, N; long doff;
    switch (blockIdx.y) {
      case 0: src=w0; K=384; N=192; doff=0;      break;
      case 1: src=w1; K=384; N=192; doff=73728;  break;
      case 2: src=w2; K=192; N=384; doff=147456; break;
      case 3: src=w3; K=192; N=192; doff=221184; break;
      case 4: src=w4; K=192; N=192; doff=258048; break;
      case 5: src=w5; K=192; N=768; doff=294912; break;
      case 6: src=w6; K=768; N=192; doff=442368; break;
      case 7: src=w7; K=192; N=768; doff=589824; break;
      default:src=w8; K=768; N=192; doff=737280; break;
    }
    int nblk = (K>>5)*(N>>6);
    int bid = blockIdx.x;
    if (bid >= nblk) return;
    int kb = bid / (N>>6), nb = bid % (N>>6);
    __shared__ float tile[32][65];
    int tid = threadIdx.x;
    #pragma unroll
    for (int it = 0; it < 8; ++it) {
        int idx = tid + it*256;
        int r = idx >> 6, c = idx & 63;
        tile[r][c] = src[(long)(kb*32 + r)*N + nb*64 + c];
    }
    __syncthreads();
    int lane = tid & 63, nl = tid >> 6;
    short8 v;
    #pragma unroll
    for (int j = 0; j < 8; ++j)
        v[j] = f2bs(tile[(lane>>4)*8 + j][nl*16 + (lane&15)]);
    long nig = (long)nb*4 + nl;
    *(short8*)(dst + doff + (((long)kb*(N>>4) + nig)*64 + lane)*8) = v;
}

// ---------------------------------------------------------------------------
// fgemm2: C = A(bf16) @ Wfrag(bf16) + bias. MR16 16-row slices per tile.
// MODE 0 plain / 1 qk-scatter / 2 v-scatter
// ---------------------------------------------------------------------------
template<int MODE, bool DUAL, int MR16>
__global__ __launch_bounds__(384)
void fgemm2(const bf16* __restrict__ A1, const bf16* __restrict__ A2, int K1, int K,
            const short* __restrict__ wf, const float* __restrict__ bias, int Nn,
            bf16* __restrict__ out, bf16* __restrict__ out2,
            const bf16* __restrict__ A1b, const bf16* __restrict__ A2b,
            const short* __restrict__ wfB, const float* __restrict__ biasB,
            bf16* __restrict__ outB, int nxblk)
{
    __shared__ short AsF[2][MR16][64][8];
    const int MROWS = MR16 * 16;
    const int MPW   = MR16 / 2;
    int tid = threadIdx.x;
    int wid = tid >> 6, lane = tid & 63;
    int wr = (wid >= 3) ? 1 : 0, wc = wid - wr*3;
    int l15 = lane & 15, g = lane >> 4;

    int bx = blockIdx.x;
    const bf16 *A1p = A1, *A2p = A2; const short* wfp = wf;
    const float* biasp = bias; bf16* outp = out;
    if (DUAL && bx >= nxblk) {
        bx -= nxblk; A1p = A1b; A2p = A2b; wfp = wfB; biasp = biasB; outp = outB;
    }
    int row0 = bx * MROWS, col0 = blockIdx.y * 192;
    const int ntiles = Nn >> 4;

    f32x4 acc[MPW][4];
    #pragma unroll
    for (int m = 0; m < MPW; m++)
        #pragma unroll
        for (int n = 0; n < 4; n++)
            acc[m][n] = (f32x4){0.f,0.f,0.f,0.f};

    int nk = K >> 5;
    #define STAGE(buf_, k0_) {                                                   \
        int colk = (k0_) + (g << 3);                                             \
        const bf16* asrc = (colk < K1) ? A1p : A2p;                              \
        int kc = (colk < K1) ? colk : colk - K1;                                 \
        if (wid < MR16)                                                          \
            gload16(asrc + (long)(row0 + wid*16 + l15)*K1 + kc,                  \
                    &AsF[buf_][wid][0][0]);                                      \
        if (MR16 == 8 && wid < 2)                                                \
            gload16(asrc + (long)(row0 + (6+wid)*16 + l15)*K1 + kc,              \
                    &AsF[buf_][(MR16==8 ? 6+wid : 0)][0][0]);                    \
    }

    STAGE(0, 0);
    __syncthreads();
    for (int t = 0; t < nk; ++t) {
        int buf = t & 1;
        if (t + 1 < nk) STAGE(buf ^ 1, (t+1) << 5);
        short8 af[MPW], bf4[4];
        #pragma unroll
        for (int m = 0; m < MPW; m++) af[m] = *((short8*)&AsF[buf][wr*MPW + m][lane][0]);
        const short* wbase = wfp + (((long)t*ntiles + (col0>>4) + wc*4)*64 + lane)*8;
        #pragma unroll
        for (int n = 0; n < 4; n++) bf4[n] = *(const short8*)(wbase + n*512);
        __builtin_amdgcn_s_setprio(1);
        #pragma unroll
        for (int m = 0; m < MPW; m++)
            #pragma unroll
            for (int n = 0; n < 4; n++)
                acc[m][n] = __builtin_amdgcn_mfma_f32_16x16x32_bf16(af[m], bf4[n], acc[m][n], 0, 0, 0);
        __builtin_amdgcn_s_setprio(0);
        __syncthreads();
    }
    #undef STAGE

    #pragma unroll
    for (int m = 0; m < MPW; m++) {
        #pragma unroll
        for (int rr = 0; rr < 4; rr++) {
            int t = row0 + wr*(MROWS/2) + m*16 + g*4 + rr;
            #pragma unroll
            for (int n2 = 0; n2 < 4; n2++) {
                int oc = col0 + wc*64 + n2*16 + l15;
                float v = acc[m][n2][rr] + biasp[oc];
                if (MODE == 0) {
                    outp[(long)t*Nn + oc] = f2b(v);
                } else if (MODE == 1) {
                    int b_ = t / NW, n = t % NW;
                    if (oc < C_DIM) {
                        int head = oc >> 5, d = oc & 31;
                        outp[(((long)b_*NH_ + head)*NW + n)*DH + d] = f2b(v * 0.17677669529663687f);
                    } else {
                        int och = oc - C_DIM;
                        int head = och >> 5, d = och & 31;
                        out2[(((long)b_*NH_ + head)*NW + n)*DH + d] = f2b(v);
                    }
                } else { // MODE 2
                    int b_ = t / NW, n = t % NW;
                    int head = oc >> 5, d = oc & 31;
                    outp[(((long)b_*NH_ + head)*NW + n)*DH + d] = f2b(v);
                }
            }
        }
    }
}

// ---------------------------------------------------------------------------
// pproj_ln2 v2: out-proj + window-reverse + unshift + residual + LN2.
// x1 kept in REGISTERS -> 19.5 KB static LDS, high occupancy.
// ---------------------------------------------------------------------------
__global__ __launch_bounds__(384)
void pproj_ln2(const bf16* __restrict__ A, const short* __restrict__ wf,
               const float* __restrict__ bias, const float* __restrict__ res,
               const float* __restrict__ g2, const float* __restrict__ b2,
               bf16* __restrict__ x1o, bf16* __restrict__ xno,
               const bf16* __restrict__ Ab, const short* __restrict__ wfB,
               const float* __restrict__ biasB, const float* __restrict__ resB,
               const float* __restrict__ g2B, const float* __restrict__ b2B,
               bf16* __restrict__ x1oB, bf16* __restrict__ xnoB,
               int nxblk)
{
    __shared__ short AsFp[2][8][64][8];   // 16384 B
    __shared__ float part[128][3][2];     //  3072 B

    int tid = threadIdx.x;
    int wid = tid >> 6, lane = tid & 63;
    int wr = (wid >= 3) ? 1 : 0, wc = wid - wr*3;
    int l15 = lane & 15, g = lane >> 4;

    int bx = blockIdx.x;
    const bf16* Ap = A; const short* wfp = wf; const float* biasp = bias;
    const float* resp = res; const float* g2p = g2; const float* b2p = b2;
    bf16* x1p = x1o; bf16* xnp = xno;
    if (bx >= nxblk) {
        bx -= nxblk; Ap = Ab; wfp = wfB; biasp = biasB; resp = resB;
        g2p = g2B; b2p = b2B; x1p = x1oB; xnp = xnoB;
    }
    int row0 = bx * 128;

    f32x4 acc[4][4];
    #pragma unroll
    for (int m = 0; m < 4; m++)
        #pragma unroll
        for (int n = 0; n < 4; n++)
            acc[m][n] = (f32x4){0.f,0.f,0.f,0.f};

    #define PSTAGE(buf_, k0_) {                                                  \
        int colk = (k0_) + (g << 3);                                             \
        if (wid < 6)                                                             \
            gload16(Ap + (long)(row0 + wid*16 + l15)*C_DIM + colk,               \
                    &AsFp[buf_][wid][0][0]);                                     \
        if (wid < 2)                                                             \
            gload16(Ap + (long)(row0 + (6+wid)*16 + l15)*C_DIM + colk,           \
                    &AsFp[buf_][6+wid][0][0]);                                   \
    }

    PSTAGE(0, 0);
    __syncthreads();
    for (int t = 0; t < 6; ++t) {
        int buf = t & 1;
        if (t + 1 < 6) PSTAGE(buf ^ 1, (t+1) << 5);
        short8 af[4], bf4[4];
        #pragma unroll
        for (int m = 0; m < 4; m++)
            af[m] = *((short8*)&AsFp[buf][wr*4 + m][lane][0]);
        const short* wbase = wfp + (((long)t*12 + wc*4)*64 + lane)*8;
        #pragma unroll
        for (int n = 0; n < 4; n++) bf4[n] = *(const short8*)(wbase + n*512);
        __builtin_amdgcn_s_setprio(1);
        #pragma unroll
        for (int m = 0; m < 4; m++)
            #pragma unroll
            for (int n = 0; n < 4; n++)
                acc[m][n] = __builtin_amdgcn_mfma_f32_16x16x32_bf16(af[m], bf4[n], acc[m][n], 0, 0, 0);
        __builtin_amdgcn_s_setprio(0);
        __syncthreads();
    }
    #undef PSTAGE

    float bias4[4], g24[4], b24[4];
    #pragma unroll
    for (int n2 = 0; n2 < 4; n2++) {
        int oc = wc*64 + n2*16 + l15;
        bias4[n2] = biasp[oc]; g24[n2] = g2p[oc]; b24[n2] = b2p[oc];
    }

    int gtv[4][4];
    #pragma unroll
    for (int m = 0; m < 4; m++) {
        #pragma unroll
        for (int rr = 0; rr < 4; rr++) {
            int t = row0 + wr*64 + m*16 + g*4 + rr;
            int b_ = t / NW, n = t - b_*NW;
            int w = b_ & (NWIN-1), b = b_ >> 6;
            int hs = (w >> 3)*WS_ + n/WS_;
            int wsf = (w & 7)*WS_ + n % WS_;
            int h = hs + SS_;  if (h >= HH)  h -= HH;
            int wc2 = wsf + SS_; if (wc2 >= WW2) wc2 -= WW2;
            int gt = b*L_TOK + h*WW2 + wc2;
            gtv[m][rr] = gt;
            int lrow = wr*64 + m*16 + g*4 + rr;
            float ps = 0.f, pss = 0.f;
            #pragma unroll
            for (int n2 = 0; n2 < 4; n2++) {
                int oc = wc*64 + n2*16 + l15;
                float x1 = resp[(long)gt*C_DIM + oc] + acc[m][n2][rr] + bias4[n2];
                acc[m][n2][rr] = x1;
                x1p[(long)gt*C_DIM + oc] = f2b(x1);
                ps += x1; pss += x1*x1;
            }
            ps  += __shfl_xor(ps, 1);  pss += __shfl_xor(pss, 1);
            ps  += __shfl_xor(ps, 2);  pss += __shfl_xor(pss, 2);
            ps  += __shfl_xor(ps, 4);  pss += __shfl_xor(pss, 4);
            ps  += __shfl_xor(ps, 8);  pss += __shfl_xor(pss, 8);
            if (l15 == 0) {
                part[lrow][wc][0] = ps;
                part[lrow][wc][1] = pss;
            }
        }
    }
    __syncthreads();

    #pragma unroll
    for (int m = 0; m < 4; m++) {
        #pragma unroll
        for (int rr = 0; rr < 4; rr++) {
            int lrow = wr*64 + m*16 + g*4 + rr;
            int gt = gtv[m][rr];
            float s  = part[lrow][0][0] + part[lrow][1][0] + part[lrow][2][0];
            float ss = part[lrow][0][1] + part[lrow][1][1] + part[lrow][2][1];
            float mean = s * (1.0f/192.0f);
            float var  = ss * (1.0f/192.0f) - mean*mean;
            float rstd = rsqrtf(var + 1e-5f);
            #pragma unroll
            for (int n2 = 0; n2 < 4; n2++) {
                int oc = wc*64 + n2*16 + l15;
                xnp[(long)gt*C_DIM + oc] = f2b((acc[m][n2][rr] - mean)*rstd*g24[n2] + b24[n2]);
            }
        }
    }
}

// ---------------------------------------------------------------------------
// mlp_fused6: as mlp_fused5 (8 x 96-col hid slices, dbuf hidS[2], 49 KB LDS,
// 3 blocks/CU) but ALL weight fragments for an interval are MANUALLY
// PRELOADED into registers before the MFMA region (12 overlapping loads),
// and setprio is applied ONCE per interval (no per-kb fences).
// ---------------------------------------------------------------------------
__global__ __launch_bounds__(384)
void mlp_fused6(const bf16* __restrict__ xn, const short* __restrict__ w1f,
                const short* __restrict__ w2f,
                const float* __restrict__ b1, const float* __restrict__ b2,
                const bf16* __restrict__ x1, float* __restrict__ dout,
                const bf16* __restrict__ xnB, const short* __restrict__ w1B,
                const short* __restrict__ w2B,
                const float* __restrict__ b1B, const float* __restrict__ b2B,
                const bf16* __restrict__ x1B, float* __restrict__ doutB,
                int nxblk)
{
    __shared__ short xnF[24*512];       // 24,576 B
    __shared__ short hidS[2][12*512];   // 24,576 B

    int tid = threadIdx.x;
    int wv = tid >> 6, lane = tid & 63;
    int l15 = lane & 15, g = lane >> 4;

    int bx = blockIdx.x;
    const bf16* xnp = xn; const short* w1p = w1f; const short* w2p = w2f;
    const float* b1p = b1; const float* b2p = b2;
    const bf16* x1p = x1; float* doutp = dout;
    if (bx >= nxblk) {
        bx -= nxblk; xnp = xnB; w1p = w1B; w2p = w2B; b1p = b1B; b2p = b2B;
        x1p = x1B; doutp = doutB;
    }
    int row0 = bx * 64;

    // stage xn tile 64x192 -> A-frag order
    #pragma unroll
    for (int p = 0; p < 4; ++p) {
        int pp = wv*4 + p;
        int a = pp / 6, kb = pp % 6;
        gload16(xnp + (long)(row0 + 16*a + l15)*C_DIM + 32*kb + 8*g,
                xnF + (a*6 + kb)*512);
    }
    __syncthreads();

    f32x4 ad[4][2];
    f32x4 au[4];
    short8 wv1[6], wv2[6];
    #pragma unroll
    for (int m = 0; m < 4; m++)
        #pragma unroll
        for (int n = 0; n < 2; n++)
            ad[m][n] = (f32x4){0.f,0.f,0.f,0.f};

    #define LOAD_W1(s_) {                                                        \
        _Pragma("unroll")                                                        \
        for (int kb = 0; kb < 6; ++kb)                                           \
            wv1[kb] = *(const short8*)(w1p + (((long)kb*48 + 6*(s_) + wv)*64 + lane)*8); \
    }
    #define LOAD_W2(s_) {                                                        \
        _Pragma("unroll")                                                        \
        for (int kb = 0; kb < 3; ++kb)                                           \
            _Pragma("unroll")                                                    \
            for (int n = 0; n < 2; ++n)                                          \
                wv2[kb*2+n] = *(const short8*)(w2p + ((((long)(3*(s_) + kb))*12 + 2*wv + n)*64 + lane)*8); \
    }
    #define UP_COMPUTE() {                                                       \
        _Pragma("unroll")                                                        \
        for (int m = 0; m < 4; m++) au[m] = (f32x4){0.f,0.f,0.f,0.f};            \
        _Pragma("unroll")                                                        \
        for (int kb = 0; kb < 6; ++kb) {                                         \
            _Pragma("unroll")                                                    \
            for (int m = 0; m < 4; m++) {                                        \
                short8 af = *(short8*)(xnF + (m*6 + kb)*512 + lane*8);           \
                au[m] = __builtin_amdgcn_mfma_f32_16x16x32_bf16(af, wv1[kb], au[m], 0, 0, 0); \
            }                                                                    \
        }                                                                        \
    }
    #define DOWN_COMPUTE(buf_) {                                                 \
        _Pragma("unroll")                                                        \
        for (int kb = 0; kb < 3; ++kb) {                                         \
            short8 hf[4];                                                        \
            _Pragma("unroll")                                                    \
            for (int m = 0; m < 4; m++)                                          \
                hf[m] = *(short8*)(&hidS[buf_][(m*3 + kb)*512] + lane*8);        \
            _Pragma("unroll")                                                    \
            for (int n = 0; n < 2; n++)                                          \
                _Pragma("unroll")                                                \
                for (int m = 0; m < 4; m++)                                      \
                    ad[m][n] = __builtin_amdgcn_mfma_f32_16x16x32_bf16(hf[m], wv2[kb*2+n], ad[m][n], 0, 0, 0); \
        }                                                                        \
    }
    #define SCATTER(s_, buf_) {                                                  \
        int hc = 16*wv + l15;                                                    \
        float bb = b1p[96*(s_) + hc];                                            \
        int kb2 = hc >> 5;                                                       \
        int Lhi = 16 * ((hc >> 3) & 3);                                          \
        int j = hc & 7;                                                          \
        _Pragma("unroll")                                                        \
        for (int m = 0; m < 4; m++) {                                            \
            _Pragma("unroll")                                                    \
            for (int rr = 0; rr < 4; rr++) {                                     \
                float v = au[m][rr] + bb;                                        \
                float gl = 0.5f * v * (1.0f + erff(v * 0.70710678118654752f));   \
                int L = (4*g + rr) + Lhi;                                        \
                hidS[buf_][(m*3 + kb2)*512 + L*8 + j] = f2bs(gl);                \
            }                                                                    \
        }                                                                        \
    }

    LOAD_W1(0);
    UP_COMPUTE();
    SCATTER(0, 0);
    __syncthreads();
    for (int s = 1; s < 8; ++s) {
        LOAD_W1(s);
        LOAD_W2(s-1);
        __builtin_amdgcn_s_setprio(1);
        UP_COMPUTE();
        DOWN_COMPUTE((s-1)&1);
        __builtin_amdgcn_s_setprio(0);
        SCATTER(s, s&1);
        __syncthreads();
    }
    LOAD_W2(7);
    DOWN_COMPUTE(1);

    #undef LOAD_W1
    #undef LOAD_W2
    #undef UP_COMPUTE
    #undef DOWN_COMPUTE
    #undef SCATTER

    // epilogue: + bias2 + x1 -> fp32 dout
    #pragma unroll
    for (int m = 0; m < 4; m++) {
        #pragma unroll
        for (int rr = 0; rr < 4; rr++) {
            int t = row0 + 16*m + 4*g + rr;
            long goff = (long)t*C_DIM;
            #pragma unroll
            for (int n = 0; n < 2; n++) {
                int oc = 32*wv + 16*n + l15;
                float v = ad[m][n][rr] + b2p[oc];
                doutp[goff + oc] = b2f(x1p[goff + oc]) + v;
            }
        }
    }
}

// ---------------------------------------------------------------------------
// mgemm fallback (fp32 weights from global): 128x64 tile, 4 waves.
// ---------------------------------------------------------------------------
#define BM 128
#define BN 64

template<int MODE>
__global__ __launch_bounds__(256)
void mgemm(const bf16* __restrict__ A1, const bf16* __restrict__ A2, int K1, int K,
           const float* __restrict__ W, const float* __restrict__ bias, int Nn,
           bf16* __restrict__ out, bf16* __restrict__ out2,
           const float* __restrict__ res_src, const bf16* __restrict__ prj,
           int t0, float* __restrict__ dout)
{
    __shared__ short AsF[8][64][8];
    __shared__ short BsF[4][64][8];
    int tid  = threadIdx.x;
    int wid  = tid >> 6, lane = tid & 63;
    int wr   = wid >> 1, wc = wid & 1;
    int row0 = blockIdx.x * BM, col0 = blockIdx.y * BN;

    f32x4 acc[4][2];
    #pragma unroll
    for (int m = 0; m < 4; m++)
        #pragma unroll
        for (int n = 0; n < 2; n++)
            acc[m][n] = (f32x4){0.f, 0.f, 0.f, 0.f};

    int ar = tid >> 2, akseg = tid & 3;
    int bc = tid & 63, bk8 = tid >> 6;

    for (int k0 = 0; k0 < K; k0 += 32) {
        {
            int col = k0 + akseg*8;
            const bf16* asrc = (col < K1) ? A1 : A2;
            int akc = (col < K1) ? col : col - K1;
            #pragma unroll
            for (int rr = 0; rr < 2; rr++) {
                int r = ar + rr*64;
                short8 av = *(const short8*)(asrc + (long)(row0 + r)*K1 + akc);
                *((short8*)&AsF[r >> 4][(r & 15) + (akseg << 4)][0]) = av;
            }
        }
        {
            short8 bv;
            #pragma unroll
            for (int j = 0; j < 8; j++)
                bv[j] = f2bs(W[(long)(k0 + bk8*8 + j)*Nn + col0 + bc]);
            *((short8*)&BsF[bc >> 4][(bc & 15) + (bk8 << 4)][0]) = bv;
        }
        __syncthreads();
        short8 af[4], bfr[2];
        #pragma unroll
        for (int m = 0; m < 4; m++) af[m]  = *((short8*)&AsF[wr*4 + m][lane][0]);
        #pragma unroll
        for (int n = 0; n < 2; n++) bfr[n] = *((short8*)&BsF[wc*2 + n][lane][0]);
        #pragma unroll
        for (int m = 0; m < 4; m++)
            #pragma unroll
            for (int n = 0; n < 2; n++)
                acc[m][n] = __builtin_amdgcn_mfma_f32_16x16x32_bf16(af[m], bfr[n], acc[m][n], 0, 0, 0);
        __syncthreads();
    }

    #pragma unroll
    for (int m = 0; m < 4; m++) {
        #pragma unroll
        for (int rr = 0; rr < 4; rr++) {
            int t = row0 + wr*64 + m*16 + (lane >> 4)*4 + rr;
            if (MODE == 4) {
                int tg = t0 + t;
                int b = tg / L_TOK, l = tg % L_TOK;
                int h = l / WW2, wcol = l % WW2;
                int hp = h - SS_;    if (hp < 0) hp += HH;
                int wp = wcol - SS_; if (wp < 0) wp += WW2;
                int b_ = b*NWIN + (hp/WS_)*8 + (wp/WS_);
                int n  = (hp%WS_)*WS_ + (wp%WS_);
                long wsoff = ((long)b_*NW + n)*C_DIM;
                long goff  = (long)tg*C_DIM;
                #pragma unroll
                for (int n2 = 0; n2 < 2; n2++) {
                    int oc = col0 + wc*32 + n2*16 + (lane & 15);
                    float v = acc[m][n2][rr] + bias[oc];
                    dout[goff + oc] = res_src[goff + oc] + b2f(prj[wsoff + oc]) + v;
                }
            } else {
                #pragma unroll
                for (int n2 = 0; n2 < 2; n2++) {
                    int oc = col0 + wc*32 + n2*16 + (lane & 15);
                    float v = acc[m][n2][rr] + bias[oc];
                    if (MODE == 0) {
                        out[(long)t*Nn + oc] = f2b(v);
                    } else if (MODE == 1) {
                        int b_ = t / NW, n = t % NW;
                        if (oc < C_DIM) {
                            int head = oc >> 5, d = oc & 31;
                            out[(((long)b_*NH_ + head)*NW + n)*DH + d] = f2b(v * 0.17677669529663687f);
                        } else {
                            int och = oc - C_DIM;
                            int head = och >> 5, d = och & 31;
                            out2[(((long)b_*NH_ + head)*NW + n)*DH + d] = f2b(v);
                        }
                    } else if (MODE == 2) {
                        int b_ = t / NW, n = t % NW;
                        int head = oc >> 5, d = oc & 31;
                        out[(((long)b_*NH_ + head)*NW + n)*DH + d] = f2b(v);
                    } else {
                        float g2 = 0.5f * v * (1.0f + erff(v * 0.70710678118654752f));
                        out[(long)t*Nn + oc] = f2b(g2);
                    }
                }
            }
        }
    }
}

// ---------------------------------------------------------------------------
// MFMA attention: 1 wave per (window,head), 2 waves/block.
// ---------------------------------------------------------------------------
#define PSTR 72
#define VSTR 72

__global__ __launch_bounds__(128)
void attn_mfma(const bf16* __restrict__ qb, const bf16* __restrict__ kb,
               const bf16* __restrict__ vse, const bf16* __restrict__ vde,
               const float* __restrict__ rpb,
               bf16* __restrict__ ose, bf16* __restrict__ ode)
{
    __shared__ float rpbs[169*NH_];
    __shared__ short P[2][64][PSTR];
    __shared__ short VTs[2][32][VSTR];
    __shared__ short VTd[2][32][VSTR];
    int tid = threadIdx.x, wid = tid >> 6, lane = tid & 63;
    for (int i = tid; i < 169*NH_; i += 128) rpbs[i] = rpb[i];
    __syncthreads();

    int bh = blockIdx.x*2 + wid;
    int b_ = bh / NH_, head = bh % NH_;
    int w = b_ & (NWIN-1);
    int wh = w >> 3, ww = w & 7;
    long base = (long)bh * (NW*DH);
    int l15 = lane & 15, g = lane >> 4;
    int j0 = lane >> 2, seg = lane & 3;

    short8 qf[4], kf[4], va_[4], vb_[4];
    #pragma unroll
    for (int mi = 0; mi < 4; mi++) {
        int r = l15 + 16*mi; if (r > 48) r = 48;
        qf[mi] = *(const short8*)(qb + base + r*DH + 8*g);
    }
    #pragma unroll
    for (int ni = 0; ni < 4; ni++) {
        int r = l15 + 16*ni; if (r > 48) r = 48;
        kf[ni] = *(const short8*)(kb + base + r*DH + 8*g);
    }
    #pragma unroll
    for (int it = 0; it < 4; ++it) {
        int j = j0 + 16*it;
        va_[it] = (short8){0,0,0,0,0,0,0,0};
        vb_[it] = (short8){0,0,0,0,0,0,0,0};
        if (j < NW) {
            va_[it] = *(const short8*)(vse + base + j*DH + seg*8);
            vb_[it] = *(const short8*)(vde + base + j*DH + seg*8);
        }
    }

    f32x4 sA[4][4];
    #pragma unroll
    for (int mi = 0; mi < 4; mi++)
        #pragma unroll
        for (int ni = 0; ni < 4; ni++)
            sA[mi][ni] = (f32x4){0.f,0.f,0.f,0.f};
    #pragma unroll
    for (int mi = 0; mi < 4; mi++)
        #pragma unroll
        for (int ni = 0; ni < 4; ni++)
            sA[mi][ni] = __builtin_amdgcn_mfma_f32_16x16x32_bf16(qf[mi], kf[ni], sA[mi][ni], 0, 0, 0);

    #pragma unroll
    for (int it = 0; it < 4; ++it) {
        int j = j0 + 16*it;
        #pragma unroll
        for (int s2 = 0; s2 < 8; ++s2) {
            VTs[wid][seg*8 + s2][j] = va_[it][s2];
            VTd[wid][seg*8 + s2][j] = vb_[it][s2];
        }
    }

    int jv[4], j7r_[4], j7c_[4], jrh_[4], jrc_[4];
    #pragma unroll
    for (int ni = 0; ni < 4; ++ni) {
        int j = 16*ni + l15;
        jv[ni] = (j < NW);
        int a = (j*37) >> 8; int c = j - 7*a;
        j7r_[ni] = a; j7c_[ni] = c;
        int jh = wh*7 + a, jw = ww*7 + c;
        jrh_[ni] = (jh >= 49) + (jh >= 53);
        jrc_[ni] = (jw >= 49) + (jw >= 53);
    }

    #pragma unroll
    for (int mi = 0; mi < 4; mi++) {
        #pragma unroll
        for (int rr = 0; rr < 4; rr++) {
            int i = 16*mi + 4*g + rr;
            int iv = (i < NW);
            int i7r = (i*37) >> 8; int i7c = i - 7*i7r;
            int ih = wh*7 + i7r, iw = ww*7 + i7c;
            int irh = (ih >= 49) + (ih >= 53), irc = (iw >= 49) + (iw >= 53);
            float e[4], sum = 0.f;
            #pragma unroll
            for (int ni = 0; ni < 4; ni++) {
                float sv;
                if (iv && jv[ni]) {
                    int ri = (i7r - j7r_[ni] + 6)*13 + (i7c - j7c_[ni] + 6);
                    float msk = (irh == jrh_[ni] && irc == jrc_[ni]) ? 0.f : -100.f;
                    sv = sA[mi][ni][rr] + rpbs[ri*NH_ + head] + msk;
                } else {
                    sv = -1e30f;
                }
                e[ni] = __expf(sv); sum += e[ni];
            }
            sum += __shfl_xor(sum, 1);
            sum += __shfl_xor(sum, 2);
            sum += __shfl_xor(sum, 4);
            sum += __shfl_xor(sum, 8);
            float inv = 1.0f / sum;
            #pragma unroll
            for (int ni = 0; ni < 4; ni++)
                P[wid][i][16*ni + l15] = f2bs(e[ni] * inv);
        }
    }
    __syncthreads();

    f32x4 o1[4][2], o2[4][2];
    #pragma unroll
    for (int mi = 0; mi < 4; mi++)
        #pragma unroll
        for (int di = 0; di < 2; di++) {
            o1[mi][di] = (f32x4){0.f,0.f,0.f,0.f};
            o2[mi][di] = (f32x4){0.f,0.f,0.f,0.f};
        }
    #pragma unroll
    for (int mi = 0; mi < 4; mi++) {
        #pragma unroll
        for (int kk = 0; kk < 2; kk++) {
            short8 ap = *((short8*)&P[wid][16*mi + l15][kk*32 + 8*g]);
            #pragma unroll
            for (int di = 0; di < 2; di++) {
                short8 bv1 = *((short8*)&VTs[wid][16*di + l15][kk*32 + 8*g]);
                o1[mi][di] = __builtin_amdgcn_mfma_f32_16x16x32_bf16(ap, bv1, o1[mi][di], 0, 0, 0);
                short8 bv2 = *((short8*)&VTd[wid][16*di + l15][kk*32 + 8*g]);
                o2[mi][di] = __builtin_amdgcn_mfma_f32_16x16x32_bf16(ap, bv2, o2[mi][di], 0, 0, 0);
            }
        }
    }

    #pragma unroll
    for (int mi = 0; mi < 4; mi++) {
        #pragma unroll
        for (int rr = 0; rr < 4; rr++) {
            int i = 16*mi + 4*g + rr;
            if (i < NW) {
                long ob = ((long)b_*NW + i)*C_DIM + head*DH;
                #pragma unroll
                for (int di = 0; di < 2; di++) {
                    ose[ob + 16*di + l15] = f2b(o1[mi][di][rr]);
                    ode[ob + 16*di + l15] = f2b(o2[mi][di][rr]);
                }
            }
        }
    }
}

// ---------------------------------------------------------------------------
// resid_ln2 (fallback path only)
// ---------------------------------------------------------------------------
__global__ void resid_ln2_kernel(const float* __restrict__ se, const float* __restrict__ de,
                                 const bf16* __restrict__ pse, const bf16* __restrict__ pde,
                                 const float* __restrict__ g2s, const float* __restrict__ bb2s,
                                 const float* __restrict__ g2d, const float* __restrict__ bb2d,
                                 bf16* __restrict__ xns, bf16* __restrict__ xnd)
{
    int t = blockIdx.x, tid = threadIdx.x;
    int b = t / L_TOK, l = t % L_TOK;
    int h = l / WW2, wc = l % WW2;
    int hp = h - SS_;  if (hp < 0) hp += HH;
    int wp = wc - SS_; if (wp < 0) wp += WW2;
    int b_ = b*NWIN + (hp/WS_)*8 + (wp/WS_);
    int n  = (hp%WS_)*WS_ + (wp%WS_);
    long wsoff = ((long)b_*NW + n)*C_DIM;
    long off   = (long)t*C_DIM;
    {
        float x0 = se[off+tid]     + b2f(pse[wsoff+tid]);
        float x1 = se[off+tid+64]  + b2f(pse[wsoff+tid+64]);
        float x2 = se[off+tid+128] + b2f(pse[wsoff+tid+128]);
        float s  = wave_sum64(x0+x1+x2);
        float ss = wave_sum64(x0*x0 + x1*x1 + x2*x2);
        float mean = s * (1.0f/192.0f);
        float var  = ss * (1.0f/192.0f) - mean*mean;
        float rstd = rsqrtf(var + 1e-5f);
        xns[off+tid]     = f2b((x0-mean)*rstd*g2s[tid]     + bb2s[tid]);
        xns[off+tid+64]  = f2b((x1-mean)*rstd*g2s[tid+64]  + bb2s[tid+64]);
        xns[off+tid+128] = f2b((x2-mean)*rstd*g2s[tid+128] + bb2s[tid+128]);
    }
    {
        float x0 = de[off+tid]     + b2f(pde[wsoff+tid]);
        float x1 = de[off+tid+64]  + b2f(pde[wsoff+tid+64]);
        float x2 = de[off+tid+128] + b2f(pde[wsoff+tid+128]);
        float s  = wave_sum64(x0+x1+x2);
        float ss = wave_sum64(x0*x0 + x1*x1 + x2*x2);
        float mean = s * (1.0f/192.0f);
        float var  = ss * (1.0f/192.0f) - mean*mean;
        float rstd = rsqrtf(var + 1e-5f);
        xnd[off+tid]     = f2b((x0-mean)*rstd*g2d[tid]     + bb2d[tid]);
        xnd[off+tid+64]  = f2b((x1-mean)*rstd*g2d[tid+64]  + bb2d[tid+64]);
        xnd[off+tid+128] = f2b((x2-mean)*rstd*g2d[tid+128] + bb2d[tid+128]);
    }
}

// ---------------------------------------------------------------------------
extern "C" void kernel_launch(void* const* d_in, const int* in_sizes, int n_in,
                              void* d_out, int out_size, void* d_ws, size_t ws_size,
                              hipStream_t stream)
{
    const float* se     = (const float*)d_in[0];
    const float* de     = (const float*)d_in[1];
    const float* co     = (const float*)d_in[2];
    const float* n1se_g = (const float*)d_in[4];
    const float* n1se_b = (const float*)d_in[5];
    const float* n1de_g = (const float*)d_in[6];
    const float* n1de_b = (const float*)d_in[7];
    const float* rpb    = (const float*)d_in[8];
    const float* vse_w  = (const float*)d_in[9];
    const float* vse_b  = (const float*)d_in[10];
    const float* vde_w  = (const float*)d_in[11];
    const float* vde_b  = (const float*)d_in[12];
    const float* qk_w   = (const float*)d_in[13];
    const float* qk_b   = (const float*)d_in[14];
    const float* pse_w  = (const float*)d_in[15];
    const float* pse_b  = (const float*)d_in[16];
    const float* pde_w  = (const float*)d_in[17];
    const float* pde_b  = (const float*)d_in[18];
    const float* n2se_g = (const float*)d_in[19];
    const float* n2se_b = (const float*)d_in[20];
    const float* n2de_g = (const float*)d_in[21];
    const float* n2de_b = (const float*)d_in[22];
    const float* mse_w1 = (const float*)d_in[23];
    const float* mse_b1 = (const float*)d_in[24];
    const float* mse_w2 = (const float*)d_in[25];
    const float* mse_b2 = (const float*)d_in[26];
    const float* mde_w1 = (const float*)d_in[27];
    const float* mde_b1 = (const float*)d_in[28];
    const float* mde_w2 = (const float*)d_in[29];
    const float* mde_b2 = (const float*)d_in[30];

    char* ws = (char*)d_ws;
    const size_t U = (size_t)TOK * C_DIM * 2;   // 19,267,584 bytes
    bf16* sw   = (bf16*)(ws + 0*U);
    bf16* dw   = (bf16*)(ws + 1*U);
    bf16* cw   = (bf16*)(ws + 2*U);
    bf16* vse  = (bf16*)(ws + 3*U);
    bf16* vde  = (bf16*)(ws + 4*U);
    bf16* ode  = (bf16*)(ws + 5*U);
    bf16* qb   = (bf16*)(ws + 0*U);
    bf16* kb   = (bf16*)(ws + 1*U);
    bf16* ose  = (bf16*)(ws + 2*U);
    bf16* x1se = (bf16*)(ws + 0*U);
    bf16* x1de = (bf16*)(ws + 1*U);
    bf16* xns  = (bf16*)(ws + 3*U);
    bf16* xnd  = (bf16*)(ws + 4*U);
    // fallback slots
    bf16* fb_pse = (bf16*)(ws + 0*U);
    bf16* fb_pde = (bf16*)(ws + 1*U);
    bf16* fb_xns = (bf16*)(ws + 2*U);
    bf16* fb_xnd = (bf16*)(ws + 3*U);
    bf16* fb_hid = (bf16*)(ws + 4*U);
    short* wfb = (short*)(ws + 6*U);            // 884,736 bf16 = 1.73 MB

    const bool frag = (ws_size >= 6*U + 884736ull*2ull);
    float* dout = (float*)d_out;
    const int CH = TOK/2;
    const int NX = TOK/128;   // 392

    if (frag)
        wconv<<<dim3(72, 9), 256, 0, stream>>>(vse_w, vde_w, qk_w, pse_w, pde_w,
                                               mse_w1, mse_w2, mde_w1, mde_w2, wfb);
    prep_kernel<<<TOK, 64, 0, stream>>>(se, de, co, n1se_g, n1se_b, n1de_g, n1de_b, sw, dw, cw);

    if (frag) {
        fgemm2<2,true,8><<<dim3(NX*2, 1), 384, 0, stream>>>(sw, cw, C_DIM, 2*C_DIM, wfb + 0, vse_b, C_DIM,
                                                            vse, nullptr,
                                                            dw, cw, wfb + 73728, vde_b, vde, NX);
        fgemm2<1,false,8><<<dim3(NX, 2), 384, 0, stream>>>(cw, cw, C_DIM, C_DIM, wfb + 147456, qk_b, 384,
                                                           qb, kb,
                                                           nullptr, nullptr, nullptr, nullptr, nullptr, 0);
    } else {
        mgemm<2><<<dim3(TOK/BM, C_DIM/BN), 256, 0, stream>>>(sw, cw, C_DIM, 2*C_DIM, vse_w, vse_b, C_DIM,
                                                             vse, nullptr, nullptr, nullptr, 0, nullptr);
        mgemm<2><<<dim3(TOK/BM, C_DIM/BN), 256, 0, stream>>>(dw, cw, C_DIM, 2*C_DIM, vde_w, vde_b, C_DIM,
                                                             vde, nullptr, nullptr, nullptr, 0, nullptr);
        mgemm<1><<<dim3(TOK/BM, 384/BN), 256, 0, stream>>>(cw, cw, C_DIM, C_DIM, qk_w, qk_b, 384,
                                                           qb, kb, nullptr, nullptr, 0, nullptr);
    }

    attn_mfma<<<BWIN*NH_/2, 128, 0, stream>>>(qb, kb, vse, vde, rpb, ose, ode);

    if (frag) {
        pproj_ln2<<<dim3(NX*2, 1), 384, 0, stream>>>(ose, wfb + 221184, pse_b, se, n2se_g, n2se_b,
                                                     x1se, xns,
                                                     ode, wfb + 258048, pde_b, de, n2de_g, n2de_b,
                                                     x1de, xnd, NX);
        mlp_fused6<<<dim3((TOK/64)*2, 1), 384, 0, stream>>>(xns, wfb + 294912, wfb + 442368,
                                                            mse_b1, mse_b2, x1se, dout,
                                                            xnd, wfb + 589824, wfb + 737280,
                                                            mde_b1, mde_b2, x1de,
                                                            dout + (size_t)TOK*C_DIM, TOK/64);
    } else {
        mgemm<0><<<dim3(TOK/BM, C_DIM/BN), 256, 0, stream>>>(ose, ose, C_DIM, C_DIM, pse_w, pse_b, C_DIM,
                                                             fb_pse, nullptr, nullptr, nullptr, 0, nullptr);
        mgemm<0><<<dim3(TOK/BM, C_DIM/BN), 256, 0, stream>>>(ode, ode, C_DIM, C_DIM, pde_w, pde_b, C_DIM,
                                                             fb_pde, nullptr, nullptr, nullptr, 0, nullptr);
        resid_ln2_kernel<<<TOK, 64, 0, stream>>>(se, de, fb_pse, fb_pde,
                                                 n2se_g, n2se_b, n2de_g, n2de_b, fb_xns, fb_xnd);
        for (int c0 = 0; c0 < 2; c0++) {
            int t0 = c0 * CH;
            mgemm<3><<<dim3(CH/BM, HID_/BN), 256, 0, stream>>>(fb_xns + (long)t0*C_DIM, fb_xns + (long)t0*C_DIM,
                                                               C_DIM, C_DIM, mse_w1, mse_b1, HID_,
                                                               fb_hid, nullptr, nullptr, nullptr, 0, nullptr);
            mgemm<4><<<dim3(CH/BM, C_DIM/BN), 256, 0, stream>>>(fb_hid, fb_hid, HID_, HID_, mse_w2, mse_b2, C_DIM,
                                                                nullptr, nullptr, se, fb_pse, t0, dout);
        }
        for (int c0 = 0; c0 < 2; c0++) {
            int t0 = c0 * CH;
            mgemm<3><<<dim3(CH/BM, HID_/BN), 256, 0, stream>>>(fb_xnd + (long)t0*C_DIM, fb_xnd + (long)t0*C_DIM,
                                                               C_DIM, C_DIM, mde_w1, mde_b1, HID_,
                                                               fb_hid, nullptr, nullptr, nullptr, 0, nullptr);
            mgemm<4><<<dim3(CH/BM, C_DIM/BN), 256, 0, stream>>>(fb_hid, fb_hid, HID_, HID_, mde_w2, mde_b2, C_DIM,
                                                                nullptr, nullptr, de, fb_pde, t0,
                                                                dout + (size_t)TOK*C_DIM);
        }
    }
}